// Round 1
// baseline (13989.070 us; speedup 1.0000x reference)
//
#include <hip/hip_runtime.h>
#include <hip/hip_bf16.h>
#include <math.h>

#define BB 4
#define DD 60
#define SS 512
#define FF 158
#define CC 64
#define HH 128
#define FC 222      // F + C
#define G3 384      // 3H
#define NN 2048     // B*S
#define BDN 240     // B*D

__device__ __forceinline__ float sigmoidf_(float x){ return 1.0f/(1.0f+__expf(-x)); }
__device__ __forceinline__ float tanhf_(float x){
    float e = __expf(-2.0f*fabsf(x));
    float t = (1.0f - e)/(1.0f + e);
    return copysignf(t, x);
}

// ---------------- transpose weights (w_ihT padded to 224 rows with zeros) -------------
__global__ void transpose_weights(const float* __restrict__ w_ih, const float* __restrict__ w_hh,
                                  float* __restrict__ w_ihT, float* __restrict__ w_hhT){
    int idx = blockIdx.x*256 + threadIdx.x;
    const int total1 = 224*G3;
    const int total2 = HH*G3;
    if (idx < total1){
        int k = idx / G3, j = idx % G3;
        w_ihT[idx] = (k < FC) ? w_ih[j*FC + k] : 0.0f;
    } else {
        int i2 = idx - total1;
        if (i2 < total2){
            int k = i2 / G3, j = i2 % G3;
            w_hhT[i2] = w_hh[j*HH + k];
        }
    }
}

// ---------------- QKV projection: rows = (b,d,s) flattened, 16 rows/block -------------
__global__ void qkv_kernel(const float* __restrict__ x,
                           const float* __restrict__ wq, const float* __restrict__ bq,
                           const float* __restrict__ wk, const float* __restrict__ bk,
                           const float* __restrict__ wv, const float* __restrict__ bv,
                           float* __restrict__ Q, float* __restrict__ K, float* __restrict__ V){
    __shared__ float x_lds[16*FF];
    int tid = threadIdx.x;
    int row0 = blockIdx.x * 16;
    for (int i = tid; i < 16*FF; i += 256){
        int r = i / FF, f = i % FF;
        x_lds[i] = x[(row0 + r)*FF + f];
    }
    __syncthreads();
    int c = tid & 63, w = tid >> 6;
    float aq[4]={0,0,0,0}, ak[4]={0,0,0,0}, av[4]={0,0,0,0};
    const float* xw = &x_lds[(w*4)*FF];
    for (int f = 0; f < FF; ++f){
        float q = wq[f*CC + c], k = wk[f*CC + c], v = wv[f*CC + c];
        #pragma unroll
        for (int i = 0; i < 4; ++i){
            float xv = xw[i*FF + f];
            aq[i] = fmaf(xv, q, aq[i]);
            ak[i] = fmaf(xv, k, ak[i]);
            av[i] = fmaf(xv, v, av[i]);
        }
    }
    float bqv = bq[c], bkv = bk[c], bvv = bv[c];
    #pragma unroll
    for (int i = 0; i < 4; ++i){
        int rr = row0 + w*4 + i;
        Q[rr*CC + c] = aq[i] + bqv;
        K[rr*CC + c] = ak[i] + bkv;
        V[rr*CC + c] = av[i] + bvv;
    }
}

// ---------------- attention: accumulate W[t] = sum_{s masked} softmax_row_s[t] --------
// grid = 240*8; block 256 (4 waves); each block: 64 query rows of one (b,d)
__global__ __launch_bounds__(256) void attn_kernel(const float* __restrict__ Q,
                                                   const float* __restrict__ K,
                                                   const int* __restrict__ mask,
                                                   float* __restrict__ Wg){
    __shared__ float k_tile[64*68];
    __shared__ float q_lds[64*68];
    __shared__ float w_lds[4*512];
    int tid  = threadIdx.x;
    int bd   = blockIdx.x >> 3;
    int s0   = (blockIdx.x & 7) * 64;
    int lane = tid & 63, wv = tid >> 6;

    for (int i = tid; i < 4*512; i += 256) w_lds[i] = 0.0f;
    // stage this block's 64 Q rows
    for (int i = tid; i < 64*64; i += 256){
        int t = i >> 6, cc = i & 63;
        q_lds[t*68 + cc] = Q[(bd*SS + s0 + t)*CC + cc];
    }
    // key-column masks for this lane's t = tb*64+lane
    float mk[8];
    #pragma unroll
    for (int tb = 0; tb < 8; ++tb) mk[tb] = (mask[bd*SS + tb*64 + lane] != 0) ? 1.0f : 0.0f;

    #pragma unroll 1
    for (int p = 0; p < 2; ++p){
        float sc[8][8];
        #pragma unroll
        for (int tb = 0; tb < 8; ++tb){
            __syncthreads();
            for (int i = tid; i < 64*64; i += 256){
                int t = i >> 6, cc = i & 63;
                k_tile[t*68 + cc] = K[(bd*SS + tb*64 + t)*CC + cc];
            }
            __syncthreads();
            #pragma unroll
            for (int rg = 0; rg < 2; ++rg){
                float acc[4] = {0,0,0,0};
                #pragma unroll
                for (int c4 = 0; c4 < 16; ++c4){
                    float4 kv = *(const float4*)&k_tile[lane*68 + c4*4];
                    #pragma unroll
                    for (int r = 0; r < 4; ++r){
                        int lrow = wv*16 + p*8 + rg*4 + r;
                        float4 qv = *(const float4*)&q_lds[lrow*68 + c4*4];
                        acc[r] += kv.x*qv.x + kv.y*qv.y + kv.z*qv.z + kv.w*qv.w;
                    }
                }
                #pragma unroll
                for (int r = 0; r < 4; ++r) sc[rg*4 + r][tb] = acc[r];
            }
        }
        // softmax + accumulate into per-wave W
        #pragma unroll
        for (int r = 0; r < 8; ++r){
            int srow = s0 + wv*16 + p*8 + r;
            float rowmask = (mask[bd*SS + srow] != 0) ? 1.0f : 0.0f;
            float sv[8];
            #pragma unroll
            for (int tb = 0; tb < 8; ++tb)
                sv[tb] = (mk[tb] != 0.0f) ? sc[r][tb]*0.125f : -1e9f;
            float m = sv[0];
            #pragma unroll
            for (int tb = 1; tb < 8; ++tb) m = fmaxf(m, sv[tb]);
            #pragma unroll
            for (int o = 1; o < 64; o <<= 1) m = fmaxf(m, __shfl_xor(m, o, 64));
            float l = 0.0f;
            #pragma unroll
            for (int tb = 0; tb < 8; ++tb){ sv[tb] = __expf(sv[tb] - m); l += sv[tb]; }
            #pragma unroll
            for (int o = 1; o < 64; o <<= 1) l += __shfl_xor(l, o, 64);
            float inv = rowmask / l;
            #pragma unroll
            for (int tb = 0; tb < 8; ++tb)
                w_lds[wv*512 + tb*64 + lane] += sv[tb] * inv;
        }
    }
    __syncthreads();
    for (int t = tid; t < 512; t += 256){
        float s = w_lds[t] + w_lds[512 + t] + w_lds[1024 + t] + w_lds[1536 + t];
        atomicAdd(&Wg[bd*SS + t], s);
    }
}

// ---------------- market[bd][c] = (W @ V)/denom ---------------------------------------
__global__ void market_kernel(const float* __restrict__ Wg, const float* __restrict__ V,
                              const int* __restrict__ mask, float* __restrict__ market){
    int bd = blockIdx.x;
    int c  = threadIdx.x; // 64 threads
    int cnt = 0;
    #pragma unroll
    for (int j = 0; j < 8; ++j) cnt += (mask[bd*SS + c + j*64] != 0) ? 1 : 0;
    #pragma unroll
    for (int o = 1; o < 64; o <<= 1) cnt += __shfl_xor(cnt, o, 64);
    float acc = 0.0f;
    for (int t = 0; t < SS; ++t)
        acc = fmaf(Wg[bd*SS + t], V[(bd*SS + t)*CC + c], acc);
    int dn = cnt < 1 ? 1 : cnt;
    market[bd*CC + c] = acc / (float)dn;
}

// ---------------- fused LN + x_proj GEMM: 8 rows/block, 128 threads -------------------
// rows ordered row = d*2048 + n  (n = b*512 + s), output XP[row][384]
__global__ void xproj_kernel(const float* __restrict__ x, const float* __restrict__ market,
                             const float* __restrict__ ln_g, const float* __restrict__ ln_b,
                             const float* __restrict__ w_ihT, const float* __restrict__ b_ih,
                             float* __restrict__ XP){
    __shared__ float aug[8*224];
    int tid  = threadIdx.x;       // 128
    int lane = tid & 63, wv = tid >> 6;
    int row0 = blockIdx.x * 8;
    for (int ri = 0; ri < 4; ++ri){
        int r   = wv*4 + ri;
        int row = row0 + r;
        int d = row / NN;
        int n = row % NN;
        int b = n >> 9, s = n & 511;
        const float* xr = &x[((b*DD + d)*SS + s)*FF];
        const float* mr = &market[(b*DD + d)*CC];
        float v0 = xr[lane];
        float v1 = xr[64 + lane];
        float v2 = (128 + lane < FF) ? xr[128 + lane] : mr[128 + lane - FF];
        float v3 = (lane < 30) ? mr[lane + 34] : 0.0f;   // k = 192+lane, always >=158 here
        float sum = v0+v1+v2+v3;
        float sq  = v0*v0 + v1*v1 + v2*v2 + v3*v3;
        #pragma unroll
        for (int o = 1; o < 64; o <<= 1){
            sum += __shfl_xor(sum, o, 64);
            sq  += __shfl_xor(sq,  o, 64);
        }
        float mu   = sum * (1.0f/222.0f);
        float var  = sq * (1.0f/222.0f) - mu*mu;
        float rstd = rsqrtf(var + 1e-5f);
        aug[r*224 + lane]       = (v0 - mu)*rstd*ln_g[lane]       + ln_b[lane];
        aug[r*224 + 64 + lane]  = (v1 - mu)*rstd*ln_g[64 + lane]  + ln_b[64 + lane];
        aug[r*224 + 128 + lane] = (v2 - mu)*rstd*ln_g[128 + lane] + ln_b[128 + lane];
        if (lane < 32){
            int k = 192 + lane;
            float val = 0.0f;
            if (k < FC) val = (v3 - mu)*rstd*ln_g[k] + ln_b[k];
            aug[r*224 + k] = val;
        }
    }
    __syncthreads();
    float acc0[8]={0,0,0,0,0,0,0,0}, acc1[8]={0,0,0,0,0,0,0,0}, acc2[8]={0,0,0,0,0,0,0,0};
    int c0 = tid, c1 = tid + 128, c2 = tid + 256;
    for (int k4 = 0; k4 < 56; ++k4){
        float4 av[8];
        #pragma unroll
        for (int r = 0; r < 8; ++r) av[r] = *(const float4*)&aug[r*224 + k4*4];
        #pragma unroll
        for (int i = 0; i < 4; ++i){
            int k = k4*4 + i;
            float w0 = w_ihT[k*G3 + c0], w1 = w_ihT[k*G3 + c1], w2 = w_ihT[k*G3 + c2];
            #pragma unroll
            for (int r = 0; r < 8; ++r){
                float a = ((const float*)&av[r])[i];
                acc0[r] = fmaf(a, w0, acc0[r]);
                acc1[r] = fmaf(a, w1, acc1[r]);
                acc2[r] = fmaf(a, w2, acc2[r]);
            }
        }
    }
    float bi0 = b_ih[c0], bi1 = b_ih[c1], bi2 = b_ih[c2];
    #pragma unroll
    for (int r = 0; r < 8; ++r){
        int row = row0 + r;
        XP[row*G3 + c0] = acc0[r] + bi0;
        XP[row*G3 + c1] = acc1[r] + bi1;
        XP[row*G3 + c2] = acc2[r] + bi2;
    }
}

// ---------------- persistent GRU over 60 days + fused output head ---------------------
// 256 blocks x 384 threads; block owns 8 sequences; h lives in LDS
__global__ __launch_bounds__(384) void gru_kernel(const float* __restrict__ XP,
                                                  const float* __restrict__ w_hhT,
                                                  const float* __restrict__ b_hh,
                                                  const float* __restrict__ w1, const float* __restrict__ b1,
                                                  const float* __restrict__ w2, const float* __restrict__ b2,
                                                  float* __restrict__ out){
    __shared__ float h_lds[8*128];
    __shared__ float hp_lds[8*G3];
    int tid  = threadIdx.x;  // 384
    int row0 = blockIdx.x * 8;
    for (int i = tid; i < 8*128; i += 384) h_lds[i] = 0.0f;
    __syncthreads();
    float bhh = b_hh[tid];
    for (int d = 0; d < DD; ++d){
        float acc[8];
        #pragma unroll
        for (int r = 0; r < 8; ++r) acc[r] = bhh;
        #pragma unroll 4
        for (int k4 = 0; k4 < 32; ++k4){
            float wa = w_hhT[(k4*4+0)*G3 + tid];
            float wb = w_hhT[(k4*4+1)*G3 + tid];
            float wc = w_hhT[(k4*4+2)*G3 + tid];
            float wd = w_hhT[(k4*4+3)*G3 + tid];
            #pragma unroll
            for (int r = 0; r < 8; ++r){
                float4 hv = *(const float4*)&h_lds[r*128 + k4*4];
                acc[r] = fmaf(hv.x, wa, acc[r]);
                acc[r] = fmaf(hv.y, wb, acc[r]);
                acc[r] = fmaf(hv.z, wc, acc[r]);
                acc[r] = fmaf(hv.w, wd, acc[r]);
            }
        }
        #pragma unroll
        for (int r = 0; r < 8; ++r) hp_lds[r*G3 + tid] = acc[r];
        __syncthreads();
        if (tid < 128){
            int cc = tid;
            #pragma unroll 2
            for (int r = 0; r < 8; ++r){
                const float* xp = &XP[(d*NN + row0 + r)*G3];
                float xr = xp[cc], xz = xp[128+cc], xn = xp[256+cc];
                float hr = hp_lds[r*G3 + cc], hz = hp_lds[r*G3 + 128 + cc], hn = hp_lds[r*G3 + 256 + cc];
                float rg = sigmoidf_(xr + hr);
                float zg = sigmoidf_(xz + hz);
                float ng = tanhf_(xn + rg*hn);
                float ho = h_lds[r*128 + cc];
                h_lds[r*128 + cc] = (1.0f - zg)*ng + zg*ho;
            }
        }
        __syncthreads();
    }
    // fused head: wave 0 only
    if (tid < 64){
        int cc = tid;
        for (int r = 0; r < 8; ++r){
            float a = b1[cc];
            for (int k = 0; k < HH; ++k)
                a = fmaf(h_lds[r*128 + k], w1[k*64 + cc], a);
            float hid = fmaxf(a, 0.0f);
            float o = hid * w2[cc];
            #pragma unroll
            for (int off = 1; off < 64; off <<= 1) o += __shfl_xor(o, off, 64);
            if (cc == 0) out[row0 + r] = o + b2[0];
        }
    }
}

extern "C" void kernel_launch(void* const* d_in, const int* in_sizes, int n_in,
                              void* d_out, int out_size, void* d_ws, size_t ws_size,
                              hipStream_t stream) {
    const float* x    = (const float*)d_in[0];
    const int*   mask = (const int*)d_in[1];
    const float* wq   = (const float*)d_in[2];
    const float* bq   = (const float*)d_in[3];
    const float* wk   = (const float*)d_in[4];
    const float* bk   = (const float*)d_in[5];
    const float* wv   = (const float*)d_in[6];
    const float* bv   = (const float*)d_in[7];
    const float* ln_g = (const float*)d_in[8];
    const float* ln_b = (const float*)d_in[9];
    const float* w_ih = (const float*)d_in[10];
    const float* w_hh = (const float*)d_in[11];
    const float* b_ih = (const float*)d_in[12];
    const float* b_hh = (const float*)d_in[13];
    const float* w1   = (const float*)d_in[14];
    const float* b1   = (const float*)d_in[15];
    const float* w2   = (const float*)d_in[16];
    const float* b2   = (const float*)d_in[17];

    float* ws = (float*)d_ws;
    // workspace layout (floats); XP aliases dead Q/K/V/W region
    float* Q      = ws;                 //  7,864,320
    float* K      = ws + 7864320;       //  7,864,320
    float* V      = ws + 15728640;      //  7,864,320
    float* Wg     = ws + 23592960;      //    122,880
    float* XP     = ws;                 // 47,185,920 (after attention phase is done)
    float* market = ws + 47185920;      //     15,360
    float* w_ihT  = ws + 47201280;      //     86,016 (224x384, zero-padded)
    float* w_hhT  = ws + 47287296;      //     49,152
    // total: 47,336,448 floats = ~181 MB

    hipMemsetAsync(Wg, 0, 122880*sizeof(float), stream);
    transpose_weights<<<528, 256, 0, stream>>>(w_ih, w_hh, w_ihT, w_hhT);
    qkv_kernel<<<7680, 256, 0, stream>>>(x, wq, bq, wk, bk, wv, bv, Q, K, V);
    attn_kernel<<<1920, 256, 0, stream>>>(Q, K, mask, Wg);
    market_kernel<<<240, 64, 0, stream>>>(Wg, V, mask, market);
    xproj_kernel<<<15360, 128, 0, stream>>>(x, market, ln_g, ln_b, w_ihT, b_ih, XP);
    gru_kernel<<<256, 384, 0, stream>>>(XP, w_hhT, b_hh, w1, b1, w2, b2, (float*)d_out);
}

// Round 2
// 1386.117 us; speedup vs baseline: 10.0923x; 10.0923x over previous
//
#include <hip/hip_runtime.h>
#include <hip/hip_bf16.h>
#include <math.h>

#define BB 4
#define DD 60
#define SS 512
#define FF 158
#define CC 64
#define HH 128
#define FC 222      // F + C
#define G3 384      // 3H
#define NN 2048     // B*S
#define BDN 240     // B*D

__device__ __forceinline__ float sigmoidf_(float x){ return 1.0f/(1.0f+__expf(-x)); }
__device__ __forceinline__ float tanhf_(float x){
    float e = __expf(-2.0f*fabsf(x));
    float t = (1.0f - e)/(1.0f + e);
    return copysignf(t, x);
}

// ---------------- transpose weights (w_ihT padded to 224 rows with zeros) -------------
__global__ void transpose_weights(const float* __restrict__ w_ih, const float* __restrict__ w_hh,
                                  float* __restrict__ w_ihT, float* __restrict__ w_hhT){
    int idx = blockIdx.x*256 + threadIdx.x;
    const int total1 = 224*G3;
    const int total2 = HH*G3;
    if (idx < total1){
        int k = idx / G3, j = idx % G3;
        w_ihT[idx] = (k < FC) ? w_ih[j*FC + k] : 0.0f;
    } else {
        int i2 = idx - total1;
        if (i2 < total2){
            int k = i2 / G3, j = i2 % G3;
            w_hhT[i2] = w_hh[j*HH + k];
        }
    }
}

// ---------------- QKV projection: rows = (b,d,s) flattened, 16 rows/block -------------
__global__ void qkv_kernel(const float* __restrict__ x,
                           const float* __restrict__ wq, const float* __restrict__ bq,
                           const float* __restrict__ wk, const float* __restrict__ bk,
                           const float* __restrict__ wv, const float* __restrict__ bv,
                           float* __restrict__ Q, float* __restrict__ K, float* __restrict__ V){
    __shared__ float x_lds[16*FF];
    int tid = threadIdx.x;
    int row0 = blockIdx.x * 16;
    for (int i = tid; i < 16*FF; i += 256){
        int r = i / FF, f = i % FF;
        x_lds[i] = x[(row0 + r)*FF + f];
    }
    __syncthreads();
    int c = tid & 63, w = tid >> 6;
    float aq[4]={0,0,0,0}, ak[4]={0,0,0,0}, av[4]={0,0,0,0};
    const float* xw = &x_lds[(w*4)*FF];
    for (int f = 0; f < FF; ++f){
        float q = wq[f*CC + c], k = wk[f*CC + c], v = wv[f*CC + c];
        #pragma unroll
        for (int i = 0; i < 4; ++i){
            float xv = xw[i*FF + f];
            aq[i] = fmaf(xv, q, aq[i]);
            ak[i] = fmaf(xv, k, ak[i]);
            av[i] = fmaf(xv, v, av[i]);
        }
    }
    float bqv = bq[c], bkv = bk[c], bvv = bv[c];
    #pragma unroll
    for (int i = 0; i < 4; ++i){
        int rr = row0 + w*4 + i;
        Q[rr*CC + c] = aq[i] + bqv;
        K[rr*CC + c] = ak[i] + bkv;
        V[rr*CC + c] = av[i] + bvv;
    }
}

// ---------------- attention: two-pass, no stored scores, no spills -------------------
// W[t] = sum_{s masked rows} exp(score[s][t])/l_s ; key-mask applied in market_kernel.
// grid = 240*8; block 256 (4 waves); block handles 64 query rows of one (b,d).
// Per-lane tile: 4 rows x 4 keys (acc[4][4]). LDS layouts [c4][row][4] keep all
// ds_read_b128 at <=2-way bank aliasing (free on gfx950).
__global__ __launch_bounds__(256) void attn_kernel(const float* __restrict__ Q,
                                                   const float* __restrict__ K,
                                                   const int* __restrict__ mask,
                                                   float* __restrict__ Wg){
    __shared__ float q_lds[16][64][4];   // [c4][row][4c]  16 KB
    __shared__ float k_lds[16][64][4];   // [c4][key][4c]  16 KB
    __shared__ float w_cols[4][512];     // per-wave W accum  8 KB
    __shared__ float mk_lds[512];        // key masks         2 KB
    __shared__ float cr_lds[64];         // rowmask/l per row

    int tid  = threadIdx.x;
    int bd   = blockIdx.x >> 3;
    int s0   = (blockIdx.x & 7) * 64;
    int lane = tid & 63, wv = tid >> 6;

    for (int i = tid; i < 4*512; i += 256) ((float*)w_cols)[i] = 0.0f;
    for (int t = tid; t < 512; t += 256) mk_lds[t] = (mask[bd*SS + t] != 0) ? 1.0f : 0.0f;
    {   // stage 64 Q rows: thread -> (row=tid>>2, quarter=tid&3), coalesced
        int r = tid >> 2, qt = tid & 3;
        const float* src = &Q[(bd*SS + s0 + r)*CC + qt*16];
        #pragma unroll
        for (int i = 0; i < 4; ++i)
            *(float4*)&q_lds[qt*4 + i][r][0] = *(const float4*)(src + i*4);
    }

    int rsub = lane & 3;          // row group within wave
    int tsub = lane >> 2;         // key group
    int r0   = wv*16 + rsub*4;    // first of this lane's 4 rows

    float lacc[4] = {0,0,0,0};
    float crv[4]  = {0,0,0,0};

    #pragma unroll 1
    for (int pass = 0; pass < 2; ++pass){
        if (pass == 1){
            #pragma unroll
            for (int i = 0; i < 4; ++i) crv[i] = cr_lds[r0 + i];
        }
        #pragma unroll 1
        for (int kt = 0; kt < 8; ++kt){
            __syncthreads();
            {   // stage 64-key tile
                int r = tid >> 2, qt = tid & 3;
                const float* src = &K[(bd*SS + kt*64 + r)*CC + qt*16];
                #pragma unroll
                for (int i = 0; i < 4; ++i)
                    *(float4*)&k_lds[qt*4 + i][r][0] = *(const float4*)(src + i*4);
            }
            __syncthreads();
            float acc[4][4] = {{0,0,0,0},{0,0,0,0},{0,0,0,0},{0,0,0,0}};
            #pragma unroll
            for (int c4 = 0; c4 < 16; ++c4){
                float4 qv[4], kv[4];
                #pragma unroll
                for (int i = 0; i < 4; ++i) qv[i] = *(const float4*)&q_lds[c4][r0 + i][0];
                #pragma unroll
                for (int j = 0; j < 4; ++j) kv[j] = *(const float4*)&k_lds[c4][tsub + 16*j][0];
                #pragma unroll
                for (int i = 0; i < 4; ++i){
                    #pragma unroll
                    for (int j = 0; j < 4; ++j){
                        acc[i][j] = fmaf(qv[i].x, kv[j].x, acc[i][j]);
                        acc[i][j] = fmaf(qv[i].y, kv[j].y, acc[i][j]);
                        acc[i][j] = fmaf(qv[i].z, kv[j].z, acc[i][j]);
                        acc[i][j] = fmaf(qv[i].w, kv[j].w, acc[i][j]);
                    }
                }
            }
            if (pass == 0){
                #pragma unroll
                for (int i = 0; i < 4; ++i){
                    float s = 0.0f;
                    #pragma unroll
                    for (int j = 0; j < 4; ++j)
                        s += __expf(acc[i][j]*0.125f) * mk_lds[kt*64 + tsub + 16*j];
                    lacc[i] += s;
                }
            } else {
                #pragma unroll
                for (int j = 0; j < 4; ++j){
                    float s = __expf(acc[0][j]*0.125f)*crv[0]
                            + __expf(acc[1][j]*0.125f)*crv[1]
                            + __expf(acc[2][j]*0.125f)*crv[2]
                            + __expf(acc[3][j]*0.125f)*crv[3];
                    s += __shfl_xor(s, 1, 64);
                    s += __shfl_xor(s, 2, 64);
                    if (rsub == 0)
                        w_cols[wv][kt*64 + tsub + 16*j] += s;
                }
            }
        }
        if (pass == 0){
            // reduce l over the 16 key-groups (lane bits 2..5)
            #pragma unroll
            for (int i = 0; i < 4; ++i){
                #pragma unroll
                for (int o = 4; o < 64; o <<= 1)
                    lacc[i] += __shfl_xor(lacc[i], o, 64);
            }
            if (tsub == 0){
                #pragma unroll
                for (int i = 0; i < 4; ++i){
                    int r = r0 + i;
                    float rowmask = (mask[bd*SS + s0 + r] != 0) ? 1.0f : 0.0f;
                    cr_lds[r] = rowmask / lacc[i];
                }
            }
            __syncthreads();
        }
    }
    __syncthreads();
    for (int t = tid; t < 512; t += 256){
        float s = w_cols[0][t] + w_cols[1][t] + w_cols[2][t] + w_cols[3][t];
        atomicAdd(&Wg[bd*SS + t], s);
    }
}

// ---------------- market[bd][c] = (W * key_mask) @ V / denom --------------------------
__global__ void market_kernel(const float* __restrict__ Wg, const float* __restrict__ V,
                              const int* __restrict__ mask, float* __restrict__ market){
    int bd = blockIdx.x;
    int c  = threadIdx.x; // 64 threads
    int cnt = 0;
    #pragma unroll
    for (int j = 0; j < 8; ++j) cnt += (mask[bd*SS + c + j*64] != 0) ? 1 : 0;
    #pragma unroll
    for (int o = 1; o < 64; o <<= 1) cnt += __shfl_xor(cnt, o, 64);
    float acc = 0.0f;
    for (int t = 0; t < SS; ++t){
        float mkt = (mask[bd*SS + t] != 0) ? 1.0f : 0.0f;
        acc = fmaf(Wg[bd*SS + t]*mkt, V[(bd*SS + t)*CC + c], acc);
    }
    int dn = cnt < 1 ? 1 : cnt;
    market[bd*CC + c] = acc / (float)dn;
}

// ---------------- fused LN + x_proj GEMM: 8 rows/block, 128 threads -------------------
// rows ordered row = d*2048 + n  (n = b*512 + s), output XP[row][384]
__global__ void xproj_kernel(const float* __restrict__ x, const float* __restrict__ market,
                             const float* __restrict__ ln_g, const float* __restrict__ ln_b,
                             const float* __restrict__ w_ihT, const float* __restrict__ b_ih,
                             float* __restrict__ XP){
    __shared__ float aug[8*224];
    int tid  = threadIdx.x;       // 128
    int lane = tid & 63, wv = tid >> 6;
    int row0 = blockIdx.x * 8;
    for (int ri = 0; ri < 4; ++ri){
        int r   = wv*4 + ri;
        int row = row0 + r;
        int d = row / NN;
        int n = row % NN;
        int b = n >> 9, s = n & 511;
        const float* xr = &x[((b*DD + d)*SS + s)*FF];
        const float* mr = &market[(b*DD + d)*CC];
        float v0 = xr[lane];
        float v1 = xr[64 + lane];
        float v2 = (128 + lane < FF) ? xr[128 + lane] : mr[128 + lane - FF];
        float v3 = (lane < 30) ? mr[lane + 34] : 0.0f;   // k = 192+lane, always >=158 here
        float sum = v0+v1+v2+v3;
        float sq  = v0*v0 + v1*v1 + v2*v2 + v3*v3;
        #pragma unroll
        for (int o = 1; o < 64; o <<= 1){
            sum += __shfl_xor(sum, o, 64);
            sq  += __shfl_xor(sq,  o, 64);
        }
        float mu   = sum * (1.0f/222.0f);
        float var  = sq * (1.0f/222.0f) - mu*mu;
        float rstd = rsqrtf(var + 1e-5f);
        aug[r*224 + lane]       = (v0 - mu)*rstd*ln_g[lane]       + ln_b[lane];
        aug[r*224 + 64 + lane]  = (v1 - mu)*rstd*ln_g[64 + lane]  + ln_b[64 + lane];
        aug[r*224 + 128 + lane] = (v2 - mu)*rstd*ln_g[128 + lane] + ln_b[128 + lane];
        if (lane < 32){
            int k = 192 + lane;
            float val = 0.0f;
            if (k < FC) val = (v3 - mu)*rstd*ln_g[k] + ln_b[k];
            aug[r*224 + k] = val;
        }
    }
    __syncthreads();
    float acc0[8]={0,0,0,0,0,0,0,0}, acc1[8]={0,0,0,0,0,0,0,0}, acc2[8]={0,0,0,0,0,0,0,0};
    int c0 = tid, c1 = tid + 128, c2 = tid + 256;
    for (int k4 = 0; k4 < 56; ++k4){
        float4 av[8];
        #pragma unroll
        for (int r = 0; r < 8; ++r) av[r] = *(const float4*)&aug[r*224 + k4*4];
        #pragma unroll
        for (int i = 0; i < 4; ++i){
            int k = k4*4 + i;
            float w0 = w_ihT[k*G3 + c0], w1 = w_ihT[k*G3 + c1], w2 = w_ihT[k*G3 + c2];
            #pragma unroll
            for (int r = 0; r < 8; ++r){
                float a = ((const float*)&av[r])[i];
                acc0[r] = fmaf(a, w0, acc0[r]);
                acc1[r] = fmaf(a, w1, acc1[r]);
                acc2[r] = fmaf(a, w2, acc2[r]);
            }
        }
    }
    float bi0 = b_ih[c0], bi1 = b_ih[c1], bi2 = b_ih[c2];
    #pragma unroll
    for (int r = 0; r < 8; ++r){
        int row = row0 + r;
        XP[row*G3 + c0] = acc0[r] + bi0;
        XP[row*G3 + c1] = acc1[r] + bi1;
        XP[row*G3 + c2] = acc2[r] + bi2;
    }
}

// ---------------- persistent GRU over 60 days + fused output head ---------------------
// 256 blocks x 384 threads; block owns 8 sequences; h lives in LDS
__global__ __launch_bounds__(384) void gru_kernel(const float* __restrict__ XP,
                                                  const float* __restrict__ w_hhT,
                                                  const float* __restrict__ b_hh,
                                                  const float* __restrict__ w1, const float* __restrict__ b1,
                                                  const float* __restrict__ w2, const float* __restrict__ b2,
                                                  float* __restrict__ out){
    __shared__ float h_lds[8*128];
    __shared__ float hp_lds[8*G3];
    int tid  = threadIdx.x;  // 384
    int row0 = blockIdx.x * 8;
    for (int i = tid; i < 8*128; i += 384) h_lds[i] = 0.0f;
    __syncthreads();
    float bhh = b_hh[tid];
    for (int d = 0; d < DD; ++d){
        float acc[8];
        #pragma unroll
        for (int r = 0; r < 8; ++r) acc[r] = bhh;
        #pragma unroll 4
        for (int k4 = 0; k4 < 32; ++k4){
            float wa = w_hhT[(k4*4+0)*G3 + tid];
            float wb = w_hhT[(k4*4+1)*G3 + tid];
            float wc = w_hhT[(k4*4+2)*G3 + tid];
            float wd = w_hhT[(k4*4+3)*G3 + tid];
            #pragma unroll
            for (int r = 0; r < 8; ++r){
                float4 hv = *(const float4*)&h_lds[r*128 + k4*4];
                acc[r] = fmaf(hv.x, wa, acc[r]);
                acc[r] = fmaf(hv.y, wb, acc[r]);
                acc[r] = fmaf(hv.z, wc, acc[r]);
                acc[r] = fmaf(hv.w, wd, acc[r]);
            }
        }
        #pragma unroll
        for (int r = 0; r < 8; ++r) hp_lds[r*G3 + tid] = acc[r];
        __syncthreads();
        if (tid < 128){
            int cc = tid;
            #pragma unroll 2
            for (int r = 0; r < 8; ++r){
                const float* xp = &XP[(d*NN + row0 + r)*G3];
                float xr = xp[cc], xz = xp[128+cc], xn = xp[256+cc];
                float hr = hp_lds[r*G3 + cc], hz = hp_lds[r*G3 + 128 + cc], hn = hp_lds[r*G3 + 256 + cc];
                float rg = sigmoidf_(xr + hr);
                float zg = sigmoidf_(xz + hz);
                float ng = tanhf_(xn + rg*hn);
                float ho = h_lds[r*128 + cc];
                h_lds[r*128 + cc] = (1.0f - zg)*ng + zg*ho;
            }
        }
        __syncthreads();
    }
    // fused head: wave 0 only
    if (tid < 64){
        int cc = tid;
        for (int r = 0; r < 8; ++r){
            float a = b1[cc];
            for (int k = 0; k < HH; ++k)
                a = fmaf(h_lds[r*128 + k], w1[k*64 + cc], a);
            float hid = fmaxf(a, 0.0f);
            float o = hid * w2[cc];
            #pragma unroll
            for (int off = 1; off < 64; off <<= 1) o += __shfl_xor(o, off, 64);
            if (cc == 0) out[row0 + r] = o + b2[0];
        }
    }
}

extern "C" void kernel_launch(void* const* d_in, const int* in_sizes, int n_in,
                              void* d_out, int out_size, void* d_ws, size_t ws_size,
                              hipStream_t stream) {
    const float* x    = (const float*)d_in[0];
    const int*   mask = (const int*)d_in[1];
    const float* wq   = (const float*)d_in[2];
    const float* bq   = (const float*)d_in[3];
    const float* wk   = (const float*)d_in[4];
    const float* bk   = (const float*)d_in[5];
    const float* wv   = (const float*)d_in[6];
    const float* bv   = (const float*)d_in[7];
    const float* ln_g = (const float*)d_in[8];
    const float* ln_b = (const float*)d_in[9];
    const float* w_ih = (const float*)d_in[10];
    const float* w_hh = (const float*)d_in[11];
    const float* b_ih = (const float*)d_in[12];
    const float* b_hh = (const float*)d_in[13];
    const float* w1   = (const float*)d_in[14];
    const float* b1   = (const float*)d_in[15];
    const float* w2   = (const float*)d_in[16];
    const float* b2   = (const float*)d_in[17];

    float* ws = (float*)d_ws;
    // workspace layout (floats); XP aliases dead Q/K/V/W region
    float* Q      = ws;                 //  7,864,320
    float* K      = ws + 7864320;       //  7,864,320
    float* V      = ws + 15728640;      //  7,864,320
    float* Wg     = ws + 23592960;      //    122,880
    float* XP     = ws;                 // 47,185,920 (after attention phase is done)
    float* market = ws + 47185920;      //     15,360
    float* w_ihT  = ws + 47201280;      //     86,016 (224x384, zero-padded)
    float* w_hhT  = ws + 47287296;      //     49,152
    // total: 47,336,448 floats = ~181 MB

    hipMemsetAsync(Wg, 0, 122880*sizeof(float), stream);
    transpose_weights<<<528, 256, 0, stream>>>(w_ih, w_hh, w_ihT, w_hhT);
    qkv_kernel<<<7680, 256, 0, stream>>>(x, wq, bq, wk, bk, wv, bv, Q, K, V);
    attn_kernel<<<1920, 256, 0, stream>>>(Q, K, mask, Wg);
    market_kernel<<<240, 64, 0, stream>>>(Wg, V, mask, market);
    xproj_kernel<<<15360, 128, 0, stream>>>(x, market, ln_g, ln_b, w_ihT, b_ih, XP);
    gru_kernel<<<256, 384, 0, stream>>>(XP, w_hhT, b_hh, w1, b1, w2, b2, (float*)d_out);
}

// Round 3
// 957.535 us; speedup vs baseline: 14.6095x; 1.4476x over previous
//
#include <hip/hip_runtime.h>
#include <hip/hip_bf16.h>
#include <math.h>

#define BB 4
#define DD 60
#define SS 512
#define FF 158
#define CC 64
#define HH 128
#define FC 222      // F + C
#define G3 384      // 3H
#define NN 2048     // B*S
#define BDN 240     // B*D

typedef short s16x8 __attribute__((ext_vector_type(8)));
typedef float f32x4 __attribute__((ext_vector_type(4)));

__device__ __forceinline__ float sigmoidf_(float x){ return 1.0f/(1.0f+__expf(-x)); }
__device__ __forceinline__ float tanhf_(float x){
    float e = __expf(-2.0f*fabsf(x));
    float t = (1.0f - e)/(1.0f + e);
    return copysignf(t, x);
}
__device__ __forceinline__ unsigned short f32_to_bf16_rne(float f){
    unsigned int u = __float_as_uint(f);
    u = (u + 0x7fffu + ((u >> 16) & 1u)) >> 16;
    return (unsigned short)u;
}

// ---------------- transpose weights (w_ihT padded to 224 rows with zeros) -------------
__global__ void transpose_weights(const float* __restrict__ w_ih, const float* __restrict__ w_hh,
                                  float* __restrict__ w_ihT, float* __restrict__ w_hhT){
    int idx = blockIdx.x*256 + threadIdx.x;
    const int total1 = 224*G3;
    const int total2 = HH*G3;
    if (idx < total1){
        int k = idx / G3, j = idx % G3;
        w_ihT[idx] = (k < FC) ? w_ih[j*FC + k] : 0.0f;
    } else {
        int i2 = idx - total1;
        if (i2 < total2){
            int k = i2 / G3, j = i2 % G3;
            w_hhT[i2] = w_hh[j*HH + k];
        }
    }
}

// ---------------- QKV projection: rows = (b,d,s) flattened, 16 rows/block -------------
__global__ void qkv_kernel(const float* __restrict__ x,
                           const float* __restrict__ wq, const float* __restrict__ bq,
                           const float* __restrict__ wk, const float* __restrict__ bk,
                           const float* __restrict__ wv, const float* __restrict__ bv,
                           float* __restrict__ Q, float* __restrict__ K, float* __restrict__ V){
    __shared__ float x_lds[16*FF];
    int tid = threadIdx.x;
    int row0 = blockIdx.x * 16;
    for (int i = tid; i < 16*FF; i += 256){
        int r = i / FF, f = i % FF;
        x_lds[i] = x[(row0 + r)*FF + f];
    }
    __syncthreads();
    int c = tid & 63, w = tid >> 6;
    float aq[4]={0,0,0,0}, ak[4]={0,0,0,0}, av[4]={0,0,0,0};
    const float* xw = &x_lds[(w*4)*FF];
    for (int f = 0; f < FF; ++f){
        float q = wq[f*CC + c], k = wk[f*CC + c], v = wv[f*CC + c];
        #pragma unroll
        for (int i = 0; i < 4; ++i){
            float xv = xw[i*FF + f];
            aq[i] = fmaf(xv, q, aq[i]);
            ak[i] = fmaf(xv, k, ak[i]);
            av[i] = fmaf(xv, v, av[i]);
        }
    }
    float bqv = bq[c], bkv = bk[c], bvv = bv[c];
    #pragma unroll
    for (int i = 0; i < 4; ++i){
        int rr = row0 + w*4 + i;
        Q[rr*CC + c] = aq[i] + bqv;
        K[rr*CC + c] = ak[i] + bkv;
        V[rr*CC + c] = av[i] + bvv;
    }
}

// ---------------- attention: two-pass, no stored scores, no spills -------------------
__global__ __launch_bounds__(256) void attn_kernel(const float* __restrict__ Q,
                                                   const float* __restrict__ K,
                                                   const int* __restrict__ mask,
                                                   float* __restrict__ Wg){
    __shared__ float q_lds[16][64][4];   // [c4][row][4c]  16 KB
    __shared__ float k_lds[16][64][4];   // [c4][key][4c]  16 KB
    __shared__ float w_cols[4][512];     // per-wave W accum  8 KB
    __shared__ float mk_lds[512];        // key masks         2 KB
    __shared__ float cr_lds[64];         // rowmask/l per row

    int tid  = threadIdx.x;
    int bd   = blockIdx.x >> 3;
    int s0   = (blockIdx.x & 7) * 64;
    int lane = tid & 63, wv = tid >> 6;

    for (int i = tid; i < 4*512; i += 256) ((float*)w_cols)[i] = 0.0f;
    for (int t = tid; t < 512; t += 256) mk_lds[t] = (mask[bd*SS + t] != 0) ? 1.0f : 0.0f;
    {
        int r = tid >> 2, qt = tid & 3;
        const float* src = &Q[(bd*SS + s0 + r)*CC + qt*16];
        #pragma unroll
        for (int i = 0; i < 4; ++i)
            *(float4*)&q_lds[qt*4 + i][r][0] = *(const float4*)(src + i*4);
    }

    int rsub = lane & 3;
    int tsub = lane >> 2;
    int r0   = wv*16 + rsub*4;

    float lacc[4] = {0,0,0,0};
    float crv[4]  = {0,0,0,0};

    #pragma unroll 1
    for (int pass = 0; pass < 2; ++pass){
        if (pass == 1){
            #pragma unroll
            for (int i = 0; i < 4; ++i) crv[i] = cr_lds[r0 + i];
        }
        #pragma unroll 1
        for (int kt = 0; kt < 8; ++kt){
            __syncthreads();
            {
                int r = tid >> 2, qt = tid & 3;
                const float* src = &K[(bd*SS + kt*64 + r)*CC + qt*16];
                #pragma unroll
                for (int i = 0; i < 4; ++i)
                    *(float4*)&k_lds[qt*4 + i][r][0] = *(const float4*)(src + i*4);
            }
            __syncthreads();
            float acc[4][4] = {{0,0,0,0},{0,0,0,0},{0,0,0,0},{0,0,0,0}};
            #pragma unroll
            for (int c4 = 0; c4 < 16; ++c4){
                float4 qv[4], kv[4];
                #pragma unroll
                for (int i = 0; i < 4; ++i) qv[i] = *(const float4*)&q_lds[c4][r0 + i][0];
                #pragma unroll
                for (int j = 0; j < 4; ++j) kv[j] = *(const float4*)&k_lds[c4][tsub + 16*j][0];
                #pragma unroll
                for (int i = 0; i < 4; ++i){
                    #pragma unroll
                    for (int j = 0; j < 4; ++j){
                        acc[i][j] = fmaf(qv[i].x, kv[j].x, acc[i][j]);
                        acc[i][j] = fmaf(qv[i].y, kv[j].y, acc[i][j]);
                        acc[i][j] = fmaf(qv[i].z, kv[j].z, acc[i][j]);
                        acc[i][j] = fmaf(qv[i].w, kv[j].w, acc[i][j]);
                    }
                }
            }
            if (pass == 0){
                #pragma unroll
                for (int i = 0; i < 4; ++i){
                    float s = 0.0f;
                    #pragma unroll
                    for (int j = 0; j < 4; ++j)
                        s += __expf(acc[i][j]*0.125f) * mk_lds[kt*64 + tsub + 16*j];
                    lacc[i] += s;
                }
            } else {
                #pragma unroll
                for (int j = 0; j < 4; ++j){
                    float s = __expf(acc[0][j]*0.125f)*crv[0]
                            + __expf(acc[1][j]*0.125f)*crv[1]
                            + __expf(acc[2][j]*0.125f)*crv[2]
                            + __expf(acc[3][j]*0.125f)*crv[3];
                    s += __shfl_xor(s, 1, 64);
                    s += __shfl_xor(s, 2, 64);
                    if (rsub == 0)
                        w_cols[wv][kt*64 + tsub + 16*j] += s;
                }
            }
        }
        if (pass == 0){
            #pragma unroll
            for (int i = 0; i < 4; ++i){
                #pragma unroll
                for (int o = 4; o < 64; o <<= 1)
                    lacc[i] += __shfl_xor(lacc[i], o, 64);
            }
            if (tsub == 0){
                #pragma unroll
                for (int i = 0; i < 4; ++i){
                    int r = r0 + i;
                    float rowmask = (mask[bd*SS + s0 + r] != 0) ? 1.0f : 0.0f;
                    cr_lds[r] = rowmask / lacc[i];
                }
            }
            __syncthreads();
        }
    }
    __syncthreads();
    for (int t = tid; t < 512; t += 256){
        float s = w_cols[0][t] + w_cols[1][t] + w_cols[2][t] + w_cols[3][t];
        atomicAdd(&Wg[bd*SS + t], s);
    }
}

// ---------------- market[bd][c] = (W * key_mask) @ V / denom --------------------------
__global__ void market_kernel(const float* __restrict__ Wg, const float* __restrict__ V,
                              const int* __restrict__ mask, float* __restrict__ market){
    int bd = blockIdx.x;
    int c  = threadIdx.x; // 64 threads
    int cnt = 0;
    #pragma unroll
    for (int j = 0; j < 8; ++j) cnt += (mask[bd*SS + c + j*64] != 0) ? 1 : 0;
    #pragma unroll
    for (int o = 1; o < 64; o <<= 1) cnt += __shfl_xor(cnt, o, 64);
    float acc = 0.0f;
    for (int t = 0; t < SS; ++t){
        float mkt = (mask[bd*SS + t] != 0) ? 1.0f : 0.0f;
        acc = fmaf(Wg[bd*SS + t]*mkt, V[(bd*SS + t)*CC + c], acc);
    }
    int dn = cnt < 1 ? 1 : cnt;
    market[bd*CC + c] = acc / (float)dn;
}

// ---------------- fused LN + x_proj GEMM: 8 rows/block, 128 threads -------------------
__global__ void xproj_kernel(const float* __restrict__ x, const float* __restrict__ market,
                             const float* __restrict__ ln_g, const float* __restrict__ ln_b,
                             const float* __restrict__ w_ihT, const float* __restrict__ b_ih,
                             float* __restrict__ XP){
    __shared__ float aug[8*224];
    int tid  = threadIdx.x;       // 128
    int lane = tid & 63, wv = tid >> 6;
    int row0 = blockIdx.x * 8;
    for (int ri = 0; ri < 4; ++ri){
        int r   = wv*4 + ri;
        int row = row0 + r;
        int d = row / NN;
        int n = row % NN;
        int b = n >> 9, s = n & 511;
        const float* xr = &x[((b*DD + d)*SS + s)*FF];
        const float* mr = &market[(b*DD + d)*CC];
        float v0 = xr[lane];
        float v1 = xr[64 + lane];
        float v2 = (128 + lane < FF) ? xr[128 + lane] : mr[128 + lane - FF];
        float v3 = (lane < 30) ? mr[lane + 34] : 0.0f;
        float sum = v0+v1+v2+v3;
        float sq  = v0*v0 + v1*v1 + v2*v2 + v3*v3;
        #pragma unroll
        for (int o = 1; o < 64; o <<= 1){
            sum += __shfl_xor(sum, o, 64);
            sq  += __shfl_xor(sq,  o, 64);
        }
        float mu   = sum * (1.0f/222.0f);
        float var  = sq * (1.0f/222.0f) - mu*mu;
        float rstd = rsqrtf(var + 1e-5f);
        aug[r*224 + lane]       = (v0 - mu)*rstd*ln_g[lane]       + ln_b[lane];
        aug[r*224 + 64 + lane]  = (v1 - mu)*rstd*ln_g[64 + lane]  + ln_b[64 + lane];
        aug[r*224 + 128 + lane] = (v2 - mu)*rstd*ln_g[128 + lane] + ln_b[128 + lane];
        if (lane < 32){
            int k = 192 + lane;
            float val = 0.0f;
            if (k < FC) val = (v3 - mu)*rstd*ln_g[k] + ln_b[k];
            aug[r*224 + k] = val;
        }
    }
    __syncthreads();
    float acc0[8]={0,0,0,0,0,0,0,0}, acc1[8]={0,0,0,0,0,0,0,0}, acc2[8]={0,0,0,0,0,0,0,0};
    int c0 = tid, c1 = tid + 128, c2 = tid + 256;
    for (int k4 = 0; k4 < 56; ++k4){
        float4 av[8];
        #pragma unroll
        for (int r = 0; r < 8; ++r) av[r] = *(const float4*)&aug[r*224 + k4*4];
        #pragma unroll
        for (int i = 0; i < 4; ++i){
            int k = k4*4 + i;
            float w0 = w_ihT[k*G3 + c0], w1 = w_ihT[k*G3 + c1], w2 = w_ihT[k*G3 + c2];
            #pragma unroll
            for (int r = 0; r < 8; ++r){
                float a = ((const float*)&av[r])[i];
                acc0[r] = fmaf(a, w0, acc0[r]);
                acc1[r] = fmaf(a, w1, acc1[r]);
                acc2[r] = fmaf(a, w2, acc2[r]);
            }
        }
    }
    float bi0 = b_ih[c0], bi1 = b_ih[c1], bi2 = b_ih[c2];
    #pragma unroll
    for (int r = 0; r < 8; ++r){
        int row = row0 + r;
        XP[row*G3 + c0] = acc0[r] + bi0;
        XP[row*G3 + c1] = acc1[r] + bi1;
        XP[row*G3 + c2] = acc2[r] + bi2;
    }
}

// ---------------- persistent GRU: bf16 MFMA recurrent GEMM + fused head ---------------
// 512 blocks x 256 threads (4 waves); block owns 4 sequences (M=4 of 16-tile).
// B = w_hh (K=128 x N=384) bf16, preloaded in VGPRs: wave wv covers N in [wv*96, wv*96+96).
// h kept in LDS as both fp32 (exact z*h path) and bf16 (MFMA A operand).
__global__ __launch_bounds__(256, 2) void gru_kernel(const float* __restrict__ XP,
                                                     const float* __restrict__ w_hh,
                                                     const float* __restrict__ b_hh,
                                                     const float* __restrict__ w1, const float* __restrict__ b1,
                                                     const float* __restrict__ w2, const float* __restrict__ b2,
                                                     float* __restrict__ out){
    __shared__ unsigned short h_bf[16][136];  // bf16 h, rows 4..15 stay zero
    __shared__ float hp_lds[4][392];          // h @ w_hh^T for 4 seqs
    __shared__ float h_f32[4][132];           // fp32 h

    int tid  = threadIdx.x;
    int lane = tid & 63, wv = tid >> 6;
    int col  = lane & 15, quad = lane >> 4;
    int row0 = blockIdx.x * 4;

    // init LDS
    for (int i = tid; i < 16*136; i += 256) ((unsigned short*)h_bf)[i] = 0;
    for (int i = tid; i < 4*132; i += 256) ((float*)h_f32)[i] = 0.0f;

    // preload B fragments: bfr[nt][kq] covers n = wv*96+nt*16+col, k = kq*32+quad*8 .. +7
    s16x8 bfr[6][4];
    #pragma unroll
    for (int nt = 0; nt < 6; ++nt){
        int n = wv*96 + nt*16 + col;
        #pragma unroll
        for (int kq = 0; kq < 4; ++kq){
            const float* wr = w_hh + n*HH + kq*32 + quad*8;
            s16x8 v;
            #pragma unroll
            for (int j = 0; j < 8; ++j) v[j] = (short)f32_to_bf16_rne(wr[j]);
            bfr[nt][kq] = v;
        }
    }

    // gate-phase work split: cc = tid&127, sgrp = tid>>7; seqs {sgrp, sgrp+2}
    int cc = tid & 127, sgrp = tid >> 7;
    float bhr = b_hh[cc], bhz = b_hh[128 + cc], bhn = b_hh[256 + cc];

    // prefetch XP for day 0
    float xc[2][3], xn_[2][3];
    {
        const float* base = XP + (size_t)(row0)*G3 + cc;
        #pragma unroll
        for (int sp = 0; sp < 2; ++sp){
            int seq = sgrp + 2*sp;
            xc[sp][0] = base[seq*G3];
            xc[sp][1] = base[seq*G3 + 128];
            xc[sp][2] = base[seq*G3 + 256];
        }
    }
    __syncthreads();

    for (int d = 0; d < DD; ++d){
        // prefetch next day's XP (overlaps MFMA + barrier)
        if (d < DD-1){
            const float* base = XP + ((size_t)(d+1)*NN + row0)*G3 + cc;
            #pragma unroll
            for (int sp = 0; sp < 2; ++sp){
                int seq = sgrp + 2*sp;
                xn_[sp][0] = base[seq*G3];
                xn_[sp][1] = base[seq*G3 + 128];
                xn_[sp][2] = base[seq*G3 + 256];
            }
        }
        // A fragments from h_bf
        s16x8 a[4];
        #pragma unroll
        for (int kq = 0; kq < 4; ++kq)
            a[kq] = *(const s16x8*)&h_bf[col][kq*32 + quad*8];
        // MFMA: 6 N-tiles x 4 K-steps
        f32x4 acc[6];
        #pragma unroll
        for (int nt = 0; nt < 6; ++nt){
            f32x4 c = {0.0f, 0.0f, 0.0f, 0.0f};
            #pragma unroll
            for (int kq = 0; kq < 4; ++kq)
                c = __builtin_amdgcn_mfma_f32_16x16x32_bf16(a[kq], bfr[nt][kq], c, 0, 0, 0);
            acc[nt] = c;
        }
        // scatter hp (rows 0..3 live in quad 0: row = reg, col = lane&15)
        if (quad == 0){
            #pragma unroll
            for (int nt = 0; nt < 6; ++nt){
                int n0 = wv*96 + nt*16 + col;
                #pragma unroll
                for (int reg = 0; reg < 4; ++reg)
                    hp_lds[reg][n0] = acc[nt][reg];
            }
        }
        __syncthreads();
        // gates: 2 (seq, cc) items per thread
        #pragma unroll
        for (int sp = 0; sp < 2; ++sp){
            int seq = sgrp + 2*sp;
            float hr = hp_lds[seq][cc]       + bhr;
            float hz = hp_lds[seq][cc + 128] + bhz;
            float hn = hp_lds[seq][cc + 256] + bhn;
            float r  = sigmoidf_(xc[sp][0] + hr);
            float z  = sigmoidf_(xc[sp][1] + hz);
            float n  = tanhf_(xc[sp][2] + r*hn);
            float ho = h_f32[seq][cc];
            float hnew = (1.0f - z)*n + z*ho;
            h_f32[seq][cc] = hnew;
            h_bf[seq][cc]  = f32_to_bf16_rne(hnew);
        }
        // rotate prefetch
        #pragma unroll
        for (int sp = 0; sp < 2; ++sp){
            xc[sp][0] = xn_[sp][0]; xc[sp][1] = xn_[sp][1]; xc[sp][2] = xn_[sp][2];
        }
        __syncthreads();
    }

    // fused head: wave 0 only, 4 rows
    if (tid < 64){
        int c2 = tid;
        #pragma unroll 1
        for (int r = 0; r < 4; ++r){
            float a0 = 0.0f, a1 = 0.0f;
            #pragma unroll 8
            for (int k = 0; k < 64; ++k){
                a0 = fmaf(h_f32[r][k],      w1[k*64 + c2],        a0);
                a1 = fmaf(h_f32[r][64 + k], w1[(64 + k)*64 + c2], a1);
            }
            float hid = fmaxf(a0 + a1 + b1[c2], 0.0f);
            float o = hid * w2[c2];
            #pragma unroll
            for (int off = 1; off < 64; off <<= 1) o += __shfl_xor(o, off, 64);
            if (c2 == 0) out[row0 + r] = o + b2[0];
        }
    }
}

extern "C" void kernel_launch(void* const* d_in, const int* in_sizes, int n_in,
                              void* d_out, int out_size, void* d_ws, size_t ws_size,
                              hipStream_t stream) {
    const float* x    = (const float*)d_in[0];
    const int*   mask = (const int*)d_in[1];
    const float* wq   = (const float*)d_in[2];
    const float* bq   = (const float*)d_in[3];
    const float* wk   = (const float*)d_in[4];
    const float* bk   = (const float*)d_in[5];
    const float* wv   = (const float*)d_in[6];
    const float* bv   = (const float*)d_in[7];
    const float* ln_g = (const float*)d_in[8];
    const float* ln_b = (const float*)d_in[9];
    const float* w_ih = (const float*)d_in[10];
    const float* w_hh = (const float*)d_in[11];
    const float* b_ih = (const float*)d_in[12];
    const float* b_hh = (const float*)d_in[13];
    const float* w1   = (const float*)d_in[14];
    const float* b1   = (const float*)d_in[15];
    const float* w2   = (const float*)d_in[16];
    const float* b2   = (const float*)d_in[17];

    float* ws = (float*)d_ws;
    float* Q      = ws;                 //  7,864,320
    float* K      = ws + 7864320;       //  7,864,320
    float* V      = ws + 15728640;      //  7,864,320
    float* Wg     = ws + 23592960;      //    122,880
    float* XP     = ws;                 // 47,185,920 (after attention phase is done)
    float* market = ws + 47185920;      //     15,360
    float* w_ihT  = ws + 47201280;      //     86,016 (224x384, zero-padded)
    float* w_hhT  = ws + 47287296;      //     49,152
    // total: ~181 MB

    hipMemsetAsync(Wg, 0, 122880*sizeof(float), stream);
    transpose_weights<<<528, 256, 0, stream>>>(w_ih, w_hh, w_ihT, w_hhT);
    qkv_kernel<<<7680, 256, 0, stream>>>(x, wq, bq, wk, bk, wv, bv, Q, K, V);
    attn_kernel<<<1920, 256, 0, stream>>>(Q, K, mask, Wg);
    market_kernel<<<240, 64, 0, stream>>>(Wg, V, mask, market);
    xproj_kernel<<<15360, 128, 0, stream>>>(x, market, ln_g, ln_b, w_ihT, b_ih, XP);
    gru_kernel<<<512, 256, 0, stream>>>(XP, w_hh, b_hh, w1, b1, w2, b2, (float*)d_out);
}

// Round 4
// 729.822 us; speedup vs baseline: 19.1678x; 1.3120x over previous
//
#include <hip/hip_runtime.h>
#include <hip/hip_bf16.h>
#include <math.h>

#define BB 4
#define DD 60
#define SS 512
#define FF 158
#define CC 64
#define HH 128
#define FC 222      // F + C
#define G3 384      // 3H
#define NN 2048     // B*S
#define BDN 240     // B*D

typedef _Float16 f16x8 __attribute__((ext_vector_type(8)));
typedef float f32x4 __attribute__((ext_vector_type(4)));

__device__ __forceinline__ float sigmoidf_(float x){ return 1.0f/(1.0f+__expf(-x)); }
__device__ __forceinline__ float tanhf_(float x){
    float e = __expf(-2.0f*fabsf(x));
    float t = (1.0f - e)/(1.0f + e);
    return copysignf(t, x);
}

// ---------------- prep: w_ih (384x222 f32) -> wf16 (384x224 f16, zero-padded) --------
__global__ void prep_kernel(const float* __restrict__ w_ih, _Float16* __restrict__ wf16){
    int idx = blockIdx.x*256 + threadIdx.x;
    if (idx < 384*224){
        int n = idx / 224, k = idx % 224;
        wf16[idx] = (k < FC) ? (_Float16)w_ih[n*FC + k] : (_Float16)0.0f;
    }
}

// ---------------- QKV projection: rows = (b,d,s) flattened, 16 rows/block -------------
__global__ void qkv_kernel(const float* __restrict__ x,
                           const float* __restrict__ wq, const float* __restrict__ bq,
                           const float* __restrict__ wk, const float* __restrict__ bk,
                           const float* __restrict__ wv, const float* __restrict__ bv,
                           float* __restrict__ Q, float* __restrict__ K, float* __restrict__ V){
    __shared__ float x_lds[16*FF];
    int tid = threadIdx.x;
    int row0 = blockIdx.x * 16;
    for (int i = tid; i < 16*FF; i += 256){
        int r = i / FF, f = i % FF;
        x_lds[i] = x[(row0 + r)*FF + f];
    }
    __syncthreads();
    int c = tid & 63, w = tid >> 6;
    float aq[4]={0,0,0,0}, ak[4]={0,0,0,0}, av[4]={0,0,0,0};
    const float* xw = &x_lds[(w*4)*FF];
    for (int f = 0; f < FF; ++f){
        float q = wq[f*CC + c], k = wk[f*CC + c], v = wv[f*CC + c];
        #pragma unroll
        for (int i = 0; i < 4; ++i){
            float xv = xw[i*FF + f];
            aq[i] = fmaf(xv, q, aq[i]);
            ak[i] = fmaf(xv, k, ak[i]);
            av[i] = fmaf(xv, v, av[i]);
        }
    }
    float bqv = bq[c], bkv = bk[c], bvv = bv[c];
    #pragma unroll
    for (int i = 0; i < 4; ++i){
        int rr = row0 + w*4 + i;
        Q[rr*CC + c] = aq[i] + bqv;
        K[rr*CC + c] = ak[i] + bkv;
        V[rr*CC + c] = av[i] + bvv;
    }
}

// ---------------- attention: two-pass, no stored scores, no spills -------------------
__global__ __launch_bounds__(256) void attn_kernel(const float* __restrict__ Q,
                                                   const float* __restrict__ K,
                                                   const int* __restrict__ mask,
                                                   float* __restrict__ Wg){
    __shared__ float q_lds[16][64][4];   // [c4][row][4c]  16 KB
    __shared__ float k_lds[16][64][4];   // [c4][key][4c]  16 KB
    __shared__ float w_cols[4][512];     // per-wave W accum  8 KB
    __shared__ float mk_lds[512];        // key masks         2 KB
    __shared__ float cr_lds[64];         // rowmask/l per row

    int tid  = threadIdx.x;
    int bd   = blockIdx.x >> 3;
    int s0   = (blockIdx.x & 7) * 64;
    int lane = tid & 63, wv = tid >> 6;

    for (int i = tid; i < 4*512; i += 256) ((float*)w_cols)[i] = 0.0f;
    for (int t = tid; t < 512; t += 256) mk_lds[t] = (mask[bd*SS + t] != 0) ? 1.0f : 0.0f;
    {
        int r = tid >> 2, qt = tid & 3;
        const float* src = &Q[(bd*SS + s0 + r)*CC + qt*16];
        #pragma unroll
        for (int i = 0; i < 4; ++i)
            *(float4*)&q_lds[qt*4 + i][r][0] = *(const float4*)(src + i*4);
    }

    int rsub = lane & 3;
    int tsub = lane >> 2;
    int r0   = wv*16 + rsub*4;

    float lacc[4] = {0,0,0,0};
    float crv[4]  = {0,0,0,0};

    #pragma unroll 1
    for (int pass = 0; pass < 2; ++pass){
        if (pass == 1){
            #pragma unroll
            for (int i = 0; i < 4; ++i) crv[i] = cr_lds[r0 + i];
        }
        #pragma unroll 1
        for (int kt = 0; kt < 8; ++kt){
            __syncthreads();
            {
                int r = tid >> 2, qt = tid & 3;
                const float* src = &K[(bd*SS + kt*64 + r)*CC + qt*16];
                #pragma unroll
                for (int i = 0; i < 4; ++i)
                    *(float4*)&k_lds[qt*4 + i][r][0] = *(const float4*)(src + i*4);
            }
            __syncthreads();
            float acc[4][4] = {{0,0,0,0},{0,0,0,0},{0,0,0,0},{0,0,0,0}};
            #pragma unroll
            for (int c4 = 0; c4 < 16; ++c4){
                float4 qv[4], kv[4];
                #pragma unroll
                for (int i = 0; i < 4; ++i) qv[i] = *(const float4*)&q_lds[c4][r0 + i][0];
                #pragma unroll
                for (int j = 0; j < 4; ++j) kv[j] = *(const float4*)&k_lds[c4][tsub + 16*j][0];
                #pragma unroll
                for (int i = 0; i < 4; ++i){
                    #pragma unroll
                    for (int j = 0; j < 4; ++j){
                        acc[i][j] = fmaf(qv[i].x, kv[j].x, acc[i][j]);
                        acc[i][j] = fmaf(qv[i].y, kv[j].y, acc[i][j]);
                        acc[i][j] = fmaf(qv[i].z, kv[j].z, acc[i][j]);
                        acc[i][j] = fmaf(qv[i].w, kv[j].w, acc[i][j]);
                    }
                }
            }
            if (pass == 0){
                #pragma unroll
                for (int i = 0; i < 4; ++i){
                    float s = 0.0f;
                    #pragma unroll
                    for (int j = 0; j < 4; ++j)
                        s += __expf(acc[i][j]*0.125f) * mk_lds[kt*64 + tsub + 16*j];
                    lacc[i] += s;
                }
            } else {
                #pragma unroll
                for (int j = 0; j < 4; ++j){
                    float s = __expf(acc[0][j]*0.125f)*crv[0]
                            + __expf(acc[1][j]*0.125f)*crv[1]
                            + __expf(acc[2][j]*0.125f)*crv[2]
                            + __expf(acc[3][j]*0.125f)*crv[3];
                    s += __shfl_xor(s, 1, 64);
                    s += __shfl_xor(s, 2, 64);
                    if (rsub == 0)
                        w_cols[wv][kt*64 + tsub + 16*j] += s;
                }
            }
        }
        if (pass == 0){
            #pragma unroll
            for (int i = 0; i < 4; ++i){
                #pragma unroll
                for (int o = 4; o < 64; o <<= 1)
                    lacc[i] += __shfl_xor(lacc[i], o, 64);
            }
            if (tsub == 0){
                #pragma unroll
                for (int i = 0; i < 4; ++i){
                    int r = r0 + i;
                    float rowmask = (mask[bd*SS + s0 + r] != 0) ? 1.0f : 0.0f;
                    cr_lds[r] = rowmask / lacc[i];
                }
            }
            __syncthreads();
        }
    }
    __syncthreads();
    for (int t = tid; t < 512; t += 256){
        float s = w_cols[0][t] + w_cols[1][t] + w_cols[2][t] + w_cols[3][t];
        atomicAdd(&Wg[bd*SS + t], s);
    }
}

// ---------------- market[bd][c] = (W * key_mask) @ V / denom --------------------------
__global__ void market_kernel(const float* __restrict__ Wg, const float* __restrict__ V,
                              const int* __restrict__ mask, float* __restrict__ market){
    int bd = blockIdx.x;
    int c  = threadIdx.x; // 64 threads
    int cnt = 0;
    #pragma unroll
    for (int j = 0; j < 8; ++j) cnt += (mask[bd*SS + c + j*64] != 0) ? 1 : 0;
    #pragma unroll
    for (int o = 1; o < 64; o <<= 1) cnt += __shfl_xor(cnt, o, 64);
    float acc = 0.0f;
    for (int t = 0; t < SS; ++t){
        float mkt = (mask[bd*SS + t] != 0) ? 1.0f : 0.0f;
        acc = fmaf(Wg[bd*SS + t]*mkt, V[(bd*SS + t)*CC + c], acc);
    }
    int dn = cnt < 1 ? 1 : cnt;
    market[bd*CC + c] = acc / (float)dn;
}

// ---------------- fused LN + x_proj f16 MFMA GEMM -------------------------------------
// 512 threads (8 waves), 64 rows/block, grid 1920. Wave wv owns N in [wv*48, wv*48+48).
// A = LN(aug) f16 in LDS fragment layout [kq][row][32]; B = wf16 preloaded (84 VGPRs).
// Output XP in f16.
__global__ __launch_bounds__(512, 2) void xproj_kernel(const float* __restrict__ x,
                             const float* __restrict__ market,
                             const float* __restrict__ ln_g, const float* __restrict__ ln_b,
                             const _Float16* __restrict__ wf16, const float* __restrict__ b_ih,
                             _Float16* __restrict__ XP){
    __shared__ _Float16 aug[7][64][32];   // 28 KB
    int tid  = threadIdx.x;
    int lane = tid & 63, wv = tid >> 6;
    int col  = lane & 15, quad = lane >> 4;
    int row0 = blockIdx.x * 64;

    // preload B fragments (independent of LDS)
    f16x8 bfr[3][7];
    #pragma unroll
    for (int nt = 0; nt < 3; ++nt){
        int n = wv*48 + nt*16 + col;
        #pragma unroll
        for (int kq = 0; kq < 7; ++kq)
            bfr[nt][kq] = *(const f16x8*)&wf16[n*224 + kq*32 + quad*8];
    }

    // LN phase: each wave does 8 rows; 8 lanes per row
    {
        int wrow = wv*8 + (lane >> 3);
        int g    = lane & 7;
        int row  = row0 + wrow;
        int d = row / NN, n = row % NN;
        int b = n >> 9, s = n & 511;
        const float* xr = &x[((size_t)((b*DD + d)*SS) + s)*FF];
        const float* mr = &market[(b*DD + d)*CC];
        float v[28];
        float sum = 0.0f, sq = 0.0f;
        #pragma unroll
        for (int j = 0; j < 28; ++j){
            int f = g + 8*j;
            float vv = 0.0f;
            if (f < FF) vv = xr[f];
            else if (f < FC) vv = mr[f - FF];
            v[j] = vv;
            sum += vv; sq += vv*vv;
        }
        sum += __shfl_xor(sum,1,64); sq += __shfl_xor(sq,1,64);
        sum += __shfl_xor(sum,2,64); sq += __shfl_xor(sq,2,64);
        sum += __shfl_xor(sum,4,64); sq += __shfl_xor(sq,4,64);
        float mu   = sum * (1.0f/222.0f);
        float var  = sq * (1.0f/222.0f) - mu*mu;
        float rstd = rsqrtf(var + 1e-5f);
        #pragma unroll
        for (int j = 0; j < 28; ++j){
            int f = g + 8*j;
            float val = (f < FC) ? ((v[j]-mu)*rstd*ln_g[f] + ln_b[f]) : 0.0f;
            aug[f>>5][wrow][f&31] = (_Float16)val;
        }
    }
    __syncthreads();

    // GEMM phase
    float bias[3];
    #pragma unroll
    for (int nt = 0; nt < 3; ++nt) bias[nt] = b_ih[wv*48 + nt*16 + col];
    #pragma unroll 1
    for (int mt = 0; mt < 4; ++mt){
        f16x8 a[7];
        #pragma unroll
        for (int kq = 0; kq < 7; ++kq)
            a[kq] = *(const f16x8*)&aug[kq][mt*16 + col][quad*8];
        #pragma unroll
        for (int nt = 0; nt < 3; ++nt){
            f32x4 c = {0.0f, 0.0f, 0.0f, 0.0f};
            #pragma unroll
            for (int kq = 0; kq < 7; ++kq)
                c = __builtin_amdgcn_mfma_f32_16x16x32_f16(a[kq], bfr[nt][kq], c, 0, 0, 0);
            int nn = wv*48 + nt*16 + col;
            #pragma unroll
            for (int reg = 0; reg < 4; ++reg){
                int m = quad*4 + reg;
                XP[(size_t)(row0 + mt*16 + m)*G3 + nn] = (_Float16)(c[reg] + bias[nt]);
            }
        }
    }
}

// ---------------- persistent GRU: f16 MFMA recurrent GEMM + fused head ----------------
// 512 blocks x 256 threads (4 waves); block owns 4 sequences.
__global__ __launch_bounds__(256, 2) void gru_kernel(const _Float16* __restrict__ XP,
                                                     const float* __restrict__ w_hh,
                                                     const float* __restrict__ b_hh,
                                                     const float* __restrict__ w1, const float* __restrict__ b1,
                                                     const float* __restrict__ w2, const float* __restrict__ b2,
                                                     float* __restrict__ out){
    __shared__ _Float16 h_hf[16][136];        // f16 h, rows 4..15 stay zero
    __shared__ float hp_lds[4][392];          // h @ w_hh^T for 4 seqs
    __shared__ float h_f32[4][132];           // fp32 h

    int tid  = threadIdx.x;
    int lane = tid & 63, wv = tid >> 6;
    int col  = lane & 15, quad = lane >> 4;
    int row0 = blockIdx.x * 4;

    for (int i = tid; i < 16*136; i += 256) ((_Float16*)h_hf)[i] = (_Float16)0.0f;
    for (int i = tid; i < 4*132; i += 256) ((float*)h_f32)[i] = 0.0f;

    // preload B fragments: n = wv*96+nt*16+col, k = kq*32+quad*8 .. +7
    f16x8 bfr[6][4];
    #pragma unroll
    for (int nt = 0; nt < 6; ++nt){
        int n = wv*96 + nt*16 + col;
        #pragma unroll
        for (int kq = 0; kq < 4; ++kq){
            const float* wr = w_hh + n*HH + kq*32 + quad*8;
            f16x8 v;
            #pragma unroll
            for (int j = 0; j < 8; ++j) v[j] = (_Float16)wr[j];
            bfr[nt][kq] = v;
        }
    }

    int cc = tid & 127, sgrp = tid >> 7;
    float bhr = b_hh[cc], bhz = b_hh[128 + cc], bhn = b_hh[256 + cc];

    float xc[2][3], xn_[2][3];
    {
        const _Float16* base = XP + (size_t)(row0)*G3 + cc;
        #pragma unroll
        for (int sp = 0; sp < 2; ++sp){
            int seq = sgrp + 2*sp;
            xc[sp][0] = (float)base[seq*G3];
            xc[sp][1] = (float)base[seq*G3 + 128];
            xc[sp][2] = (float)base[seq*G3 + 256];
        }
    }
    __syncthreads();

    for (int d = 0; d < DD; ++d){
        if (d < DD-1){
            const _Float16* base = XP + ((size_t)(d+1)*NN + row0)*G3 + cc;
            #pragma unroll
            for (int sp = 0; sp < 2; ++sp){
                int seq = sgrp + 2*sp;
                xn_[sp][0] = (float)base[seq*G3];
                xn_[sp][1] = (float)base[seq*G3 + 128];
                xn_[sp][2] = (float)base[seq*G3 + 256];
            }
        }
        f16x8 a[4];
        #pragma unroll
        for (int kq = 0; kq < 4; ++kq)
            a[kq] = *(const f16x8*)&h_hf[col][kq*32 + quad*8];
        f32x4 acc[6];
        #pragma unroll
        for (int nt = 0; nt < 6; ++nt){
            f32x4 c = {0.0f, 0.0f, 0.0f, 0.0f};
            #pragma unroll
            for (int kq = 0; kq < 4; ++kq)
                c = __builtin_amdgcn_mfma_f32_16x16x32_f16(a[kq], bfr[nt][kq], c, 0, 0, 0);
            acc[nt] = c;
        }
        if (quad == 0){
            #pragma unroll
            for (int nt = 0; nt < 6; ++nt){
                int n0 = wv*96 + nt*16 + col;
                #pragma unroll
                for (int reg = 0; reg < 4; ++reg)
                    hp_lds[reg][n0] = acc[nt][reg];
            }
        }
        __syncthreads();
        #pragma unroll
        for (int sp = 0; sp < 2; ++sp){
            int seq = sgrp + 2*sp;
            float hr = hp_lds[seq][cc]       + bhr;
            float hz = hp_lds[seq][cc + 128] + bhz;
            float hn = hp_lds[seq][cc + 256] + bhn;
            float r  = sigmoidf_(xc[sp][0] + hr);
            float z  = sigmoidf_(xc[sp][1] + hz);
            float n  = tanhf_(xc[sp][2] + r*hn);
            float ho = h_f32[seq][cc];
            float hnew = (1.0f - z)*n + z*ho;
            h_f32[seq][cc] = hnew;
            h_hf[seq][cc]  = (_Float16)hnew;
        }
        #pragma unroll
        for (int sp = 0; sp < 2; ++sp){
            xc[sp][0] = xn_[sp][0]; xc[sp][1] = xn_[sp][1]; xc[sp][2] = xn_[sp][2];
        }
        __syncthreads();
    }

    if (tid < 64){
        int c2 = tid;
        #pragma unroll 1
        for (int r = 0; r < 4; ++r){
            float a0 = 0.0f, a1 = 0.0f;
            #pragma unroll 8
            for (int k = 0; k < 64; ++k){
                a0 = fmaf(h_f32[r][k],      w1[k*64 + c2],        a0);
                a1 = fmaf(h_f32[r][64 + k], w1[(64 + k)*64 + c2], a1);
            }
            float hid = fmaxf(a0 + a1 + b1[c2], 0.0f);
            float o = hid * w2[c2];
            #pragma unroll
            for (int off = 1; off < 64; off <<= 1) o += __shfl_xor(o, off, 64);
            if (c2 == 0) out[row0 + r] = o + b2[0];
        }
    }
}

extern "C" void kernel_launch(void* const* d_in, const int* in_sizes, int n_in,
                              void* d_out, int out_size, void* d_ws, size_t ws_size,
                              hipStream_t stream) {
    const float* x    = (const float*)d_in[0];
    const int*   mask = (const int*)d_in[1];
    const float* wq   = (const float*)d_in[2];
    const float* bq   = (const float*)d_in[3];
    const float* wk   = (const float*)d_in[4];
    const float* bk   = (const float*)d_in[5];
    const float* wv   = (const float*)d_in[6];
    const float* bv   = (const float*)d_in[7];
    const float* ln_g = (const float*)d_in[8];
    const float* ln_b = (const float*)d_in[9];
    const float* w_ih = (const float*)d_in[10];
    const float* w_hh = (const float*)d_in[11];
    const float* b_ih = (const float*)d_in[12];
    const float* b_hh = (const float*)d_in[13];
    const float* w1   = (const float*)d_in[14];
    const float* b1   = (const float*)d_in[15];
    const float* w2   = (const float*)d_in[16];
    const float* b2   = (const float*)d_in[17];

    float* ws = (float*)d_ws;
    float* Q      = ws;                 //  7,864,320 f32
    float* K      = ws + 7864320;       //  7,864,320 f32
    float* V      = ws + 15728640;      //  7,864,320 f32
    float* Wg     = ws + 23592960;      //    122,880 f32
    _Float16* XP  = (_Float16*)ws;      // 47,185,920 f16 = exactly the Q/K/V region (dead by then)
    float* market = ws + 47185920;      //     15,360 f32
    _Float16* wf16= (_Float16*)(ws + 47201280); // 86,016 f16

    hipMemsetAsync(Wg, 0, 122880*sizeof(float), stream);
    prep_kernel<<<336, 256, 0, stream>>>(w_ih, wf16);
    qkv_kernel<<<7680, 256, 0, stream>>>(x, wq, bq, wk, bk, wv, bv, Q, K, V);
    attn_kernel<<<1920, 256, 0, stream>>>(Q, K, mask, Wg);
    market_kernel<<<240, 64, 0, stream>>>(Wg, V, mask, market);
    xproj_kernel<<<1920, 512, 0, stream>>>(x, market, ln_g, ln_b, wf16, b_ih, XP);
    gru_kernel<<<512, 256, 0, stream>>>(XP, w_hh, b_hh, w1, b1, w2, b2, (float*)d_out);
}

// Round 5
// 483.060 us; speedup vs baseline: 28.9593x; 1.5108x over previous
//
#include <hip/hip_runtime.h>
#include <hip/hip_bf16.h>
#include <math.h>

#define BB 4
#define DD 60
#define SS 512
#define FF 158
#define CC 64
#define HH 128
#define FC 222      // F + C
#define G3 384      // 3H
#define NN 2048     // B*S
#define BDN 240     // B*D

typedef _Float16 f16x8 __attribute__((ext_vector_type(8)));
typedef float f32x4 __attribute__((ext_vector_type(4)));

__device__ __forceinline__ float sigmoidf_(float x){ return 1.0f/(1.0f+__expf(-x)); }
__device__ __forceinline__ float tanhf_(float x){
    float e = __expf(-2.0f*fabsf(x));
    float t = (1.0f - e)/(1.0f + e);
    return copysignf(t, x);
}

// ---------------- prep: wf16 (384x224) for xproj, wqkv (192x160) for qkv --------------
__global__ void prep_kernel(const float* __restrict__ w_ih,
                            const float* __restrict__ wq, const float* __restrict__ wk,
                            const float* __restrict__ wv,
                            _Float16* __restrict__ wf16, _Float16* __restrict__ wqkv){
    int idx = blockIdx.x*256 + threadIdx.x;
    if (idx < 384*224){
        int n = idx / 224, k = idx % 224;
        wf16[idx] = (k < FC) ? (_Float16)w_ih[n*FC + k] : (_Float16)0.0f;
    } else {
        int i2 = idx - 384*224;
        if (i2 < 192*160){
            int n = i2 / 160, k = i2 % 160;
            float v = 0.0f;
            if (k < FF){
                if (n < 64)       v = wq[k*CC + n];
                else if (n < 128) v = wk[k*CC + (n-64)];
                else              v = wv[k*CC + (n-128)];
            }
            wqkv[i2] = (_Float16)v;
        }
    }
}

// ---------------- QKV via f16 MFMA: 64 rows/block, 256 thr (4 waves) ------------------
// Wave wv owns N-slice [wv*48, wv*48+48): n<64 -> Q(f16), <128 -> K(f16), else V(f32).
__global__ __launch_bounds__(256) void qkv_kernel(const float* __restrict__ x,
                           const _Float16* __restrict__ wqkv,
                           const float* __restrict__ bq, const float* __restrict__ bk,
                           const float* __restrict__ bv,
                           _Float16* __restrict__ Qh, _Float16* __restrict__ Kh,
                           float* __restrict__ V){
    __shared__ _Float16 xa[5][64][40];   // fragment layout, 25.6 KB
    int tid  = threadIdx.x;
    int lane = tid & 63, wv = tid >> 6;
    int col  = lane & 15, quad = lane >> 4;
    int row0 = blockIdx.x * 64;

    // preload B fragments: 3 nt x 5 kq
    f16x8 bfr[3][5];
    #pragma unroll
    for (int nt = 0; nt < 3; ++nt){
        int n = wv*48 + nt*16 + col;
        #pragma unroll
        for (int kq = 0; kq < 5; ++kq)
            bfr[nt][kq] = *(const f16x8*)&wqkv[n*160 + kq*32 + quad*8];
    }

    // stage x (f32 -> f16 fragments)
    for (int i = tid; i < 64*160; i += 256){
        int r = i / 160, k = i % 160;
        float v = (k < FF) ? x[(size_t)(row0 + r)*FF + k] : 0.0f;
        xa[k >> 5][r][k & 31] = (_Float16)v;
    }
    __syncthreads();

    float bias[3];
    #pragma unroll
    for (int nt = 0; nt < 3; ++nt){
        int n = wv*48 + nt*16 + col;
        bias[nt] = (n < 64) ? bq[n] : (n < 128 ? bk[n-64] : bv[n-128]);
    }

    #pragma unroll 1
    for (int mt = 0; mt < 4; ++mt){
        f16x8 a[5];
        #pragma unroll
        for (int kq = 0; kq < 5; ++kq)
            a[kq] = *(const f16x8*)&xa[kq][mt*16 + col][quad*8];
        #pragma unroll
        for (int nt = 0; nt < 3; ++nt){
            f32x4 c = {0.0f, 0.0f, 0.0f, 0.0f};
            #pragma unroll
            for (int kq = 0; kq < 5; ++kq)
                c = __builtin_amdgcn_mfma_f32_16x16x32_f16(a[kq], bfr[nt][kq], c, 0, 0, 0);
            int n = wv*48 + nt*16 + col;
            #pragma unroll
            for (int reg = 0; reg < 4; ++reg){
                int row = row0 + mt*16 + quad*4 + reg;
                float val = c[reg] + bias[nt];
                if (n < 64)       Qh[(size_t)row*CC + n]       = (_Float16)val;
                else if (n < 128) Kh[(size_t)row*CC + (n-64)]  = (_Float16)val;
                else              V [(size_t)row*CC + (n-128)] = val;
            }
        }
    }
}

// ---------------- attention via f16 MFMA: no LDS staging, two-pass --------------------
// grid 240*8; 256 thr (4 waves); wave wv owns 16 query rows s0+wv*16..+15.
// A-frags (Q rows) live in 8 VGPRs across both passes; B-frags stream from global (L1/L2).
__global__ __launch_bounds__(256) void attn_kernel(const _Float16* __restrict__ Qh,
                                                   const _Float16* __restrict__ Kh,
                                                   const int* __restrict__ mask,
                                                   float* __restrict__ Wg){
    __shared__ float w_cols[4][512];   // per-wave W accum  8 KB
    __shared__ float mk_lds[512];      // key masks         2 KB

    int tid  = threadIdx.x;
    int bd   = blockIdx.x >> 3;
    int s0   = (blockIdx.x & 7) * 64;
    int lane = tid & 63, wv = tid >> 6;
    int col  = lane & 15, quad = lane >> 4;

    for (int i = tid; i < 4*512; i += 256) ((float*)w_cols)[i] = 0.0f;
    for (int t = tid; t < 512; t += 256) mk_lds[t] = (mask[bd*SS + t] != 0) ? 1.0f : 0.0f;

    const _Float16* qb = Qh + (size_t)(bd*SS)*CC;
    const _Float16* kb = Kh + (size_t)(bd*SS)*CC;

    // A fragments: row = s0 + wv*16 + col, fixed for both passes
    f16x8 a0 = *(const f16x8*)&qb[(s0 + wv*16 + col)*CC + quad*8];
    f16x8 a1 = *(const f16x8*)&qb[(s0 + wv*16 + col)*CC + 32 + quad*8];

    __syncthreads();

    // ---- pass 0: row sums l ----
    float lacc[4] = {0,0,0,0};
    #pragma unroll 1
    for (int kt = 0; kt < 8; ++kt){
        #pragma unroll
        for (int nt = 0; nt < 4; ++nt){
            int t = kt*64 + nt*16 + col;
            f16x8 b0 = *(const f16x8*)&kb[t*CC + quad*8];
            f16x8 b1 = *(const f16x8*)&kb[t*CC + 32 + quad*8];
            f32x4 c = {0.0f, 0.0f, 0.0f, 0.0f};
            c = __builtin_amdgcn_mfma_f32_16x16x32_f16(a0, b0, c, 0, 0, 0);
            c = __builtin_amdgcn_mfma_f32_16x16x32_f16(a1, b1, c, 0, 0, 0);
            float mkv = mk_lds[t];
            #pragma unroll
            for (int reg = 0; reg < 4; ++reg)
                lacc[reg] += __expf(c[reg]*0.125f) * mkv;
        }
    }
    // reduce over the 16 col-lanes -> full row sums
    #pragma unroll
    for (int reg = 0; reg < 4; ++reg){
        lacc[reg] += __shfl_xor(lacc[reg], 1, 64);
        lacc[reg] += __shfl_xor(lacc[reg], 2, 64);
        lacc[reg] += __shfl_xor(lacc[reg], 4, 64);
        lacc[reg] += __shfl_xor(lacc[reg], 8, 64);
    }
    float crv[4];
    #pragma unroll
    for (int reg = 0; reg < 4; ++reg){
        int srow = s0 + wv*16 + quad*4 + reg;
        crv[reg] = mk_lds[srow] / lacc[reg];
    }

    // ---- pass 1: accumulate W columns ----
    #pragma unroll 1
    for (int kt = 0; kt < 8; ++kt){
        #pragma unroll
        for (int nt = 0; nt < 4; ++nt){
            int t = kt*64 + nt*16 + col;
            f16x8 b0 = *(const f16x8*)&kb[t*CC + quad*8];
            f16x8 b1 = *(const f16x8*)&kb[t*CC + 32 + quad*8];
            f32x4 c = {0.0f, 0.0f, 0.0f, 0.0f};
            c = __builtin_amdgcn_mfma_f32_16x16x32_f16(a0, b0, c, 0, 0, 0);
            c = __builtin_amdgcn_mfma_f32_16x16x32_f16(a1, b1, c, 0, 0, 0);
            float s = __expf(c[0]*0.125f)*crv[0]
                    + __expf(c[1]*0.125f)*crv[1]
                    + __expf(c[2]*0.125f)*crv[2]
                    + __expf(c[3]*0.125f)*crv[3];
            s += __shfl_xor(s, 16, 64);
            s += __shfl_xor(s, 32, 64);
            if (quad == 0)
                w_cols[wv][t] += s;
        }
    }
    __syncthreads();
    for (int t = tid; t < 512; t += 256){
        float s = w_cols[0][t] + w_cols[1][t] + w_cols[2][t] + w_cols[3][t];
        atomicAdd(&Wg[bd*SS + t], s);
    }
}

// ---------------- market[bd][c] = (W * key_mask) @ V / denom --------------------------
__global__ void market_kernel(const float* __restrict__ Wg, const float* __restrict__ V,
                              const int* __restrict__ mask, float* __restrict__ market){
    int bd = blockIdx.x;
    int c  = threadIdx.x; // 64 threads
    int cnt = 0;
    #pragma unroll
    for (int j = 0; j < 8; ++j) cnt += (mask[bd*SS + c + j*64] != 0) ? 1 : 0;
    #pragma unroll
    for (int o = 1; o < 64; o <<= 1) cnt += __shfl_xor(cnt, o, 64);
    float acc = 0.0f;
    for (int t = 0; t < SS; ++t){
        float mkt = (mask[bd*SS + t] != 0) ? 1.0f : 0.0f;
        acc = fmaf(Wg[bd*SS + t]*mkt, V[(size_t)(bd*SS + t)*CC + c], acc);
    }
    int dn = cnt < 1 ? 1 : cnt;
    market[bd*CC + c] = acc / (float)dn;
}

// ---------------- fused LN + x_proj f16 MFMA GEMM -------------------------------------
__global__ __launch_bounds__(512, 2) void xproj_kernel(const float* __restrict__ x,
                             const float* __restrict__ market,
                             const float* __restrict__ ln_g, const float* __restrict__ ln_b,
                             const _Float16* __restrict__ wf16, const float* __restrict__ b_ih,
                             _Float16* __restrict__ XP){
    __shared__ _Float16 aug[7][64][32];   // 28 KB
    int tid  = threadIdx.x;
    int lane = tid & 63, wv = tid >> 6;
    int col  = lane & 15, quad = lane >> 4;
    int row0 = blockIdx.x * 64;

    f16x8 bfr[3][7];
    #pragma unroll
    for (int nt = 0; nt < 3; ++nt){
        int n = wv*48 + nt*16 + col;
        #pragma unroll
        for (int kq = 0; kq < 7; ++kq)
            bfr[nt][kq] = *(const f16x8*)&wf16[n*224 + kq*32 + quad*8];
    }

    {
        int wrow = wv*8 + (lane >> 3);
        int g    = lane & 7;
        int row  = row0 + wrow;
        int d = row / NN, n = row % NN;
        int b = n >> 9, s = n & 511;
        const float* xr = &x[((size_t)((b*DD + d)*SS) + s)*FF];
        const float* mr = &market[(b*DD + d)*CC];
        float v[28];
        float sum = 0.0f, sq = 0.0f;
        #pragma unroll
        for (int j = 0; j < 28; ++j){
            int f = g + 8*j;
            float vv = 0.0f;
            if (f < FF) vv = xr[f];
            else if (f < FC) vv = mr[f - FF];
            v[j] = vv;
            sum += vv; sq += vv*vv;
        }
        sum += __shfl_xor(sum,1,64); sq += __shfl_xor(sq,1,64);
        sum += __shfl_xor(sum,2,64); sq += __shfl_xor(sq,2,64);
        sum += __shfl_xor(sum,4,64); sq += __shfl_xor(sq,4,64);
        float mu   = sum * (1.0f/222.0f);
        float var  = sq * (1.0f/222.0f) - mu*mu;
        float rstd = rsqrtf(var + 1e-5f);
        #pragma unroll
        for (int j = 0; j < 28; ++j){
            int f = g + 8*j;
            float val = (f < FC) ? ((v[j]-mu)*rstd*ln_g[f] + ln_b[f]) : 0.0f;
            aug[f>>5][wrow][f&31] = (_Float16)val;
        }
    }
    __syncthreads();

    float bias[3];
    #pragma unroll
    for (int nt = 0; nt < 3; ++nt) bias[nt] = b_ih[wv*48 + nt*16 + col];
    #pragma unroll 1
    for (int mt = 0; mt < 4; ++mt){
        f16x8 a[7];
        #pragma unroll
        for (int kq = 0; kq < 7; ++kq)
            a[kq] = *(const f16x8*)&aug[kq][mt*16 + col][quad*8];
        #pragma unroll
        for (int nt = 0; nt < 3; ++nt){
            f32x4 c = {0.0f, 0.0f, 0.0f, 0.0f};
            #pragma unroll
            for (int kq = 0; kq < 7; ++kq)
                c = __builtin_amdgcn_mfma_f32_16x16x32_f16(a[kq], bfr[nt][kq], c, 0, 0, 0);
            int nn = wv*48 + nt*16 + col;
            #pragma unroll
            for (int reg = 0; reg < 4; ++reg){
                int m = quad*4 + reg;
                XP[(size_t)(row0 + mt*16 + m)*G3 + nn] = (_Float16)(c[reg] + bias[nt]);
            }
        }
    }
}

// ---------------- persistent GRU: f16 MFMA recurrent GEMM + fused head ----------------
__global__ __launch_bounds__(256, 2) void gru_kernel(const _Float16* __restrict__ XP,
                                                     const float* __restrict__ w_hh,
                                                     const float* __restrict__ b_hh,
                                                     const float* __restrict__ w1, const float* __restrict__ b1,
                                                     const float* __restrict__ w2, const float* __restrict__ b2,
                                                     float* __restrict__ out){
    __shared__ _Float16 h_hf[16][136];
    __shared__ float hp_lds[4][392];
    __shared__ float h_f32[4][132];

    int tid  = threadIdx.x;
    int lane = tid & 63, wv = tid >> 6;
    int col  = lane & 15, quad = lane >> 4;
    int row0 = blockIdx.x * 4;

    for (int i = tid; i < 16*136; i += 256) ((_Float16*)h_hf)[i] = (_Float16)0.0f;
    for (int i = tid; i < 4*132; i += 256) ((float*)h_f32)[i] = 0.0f;

    f16x8 bfr[6][4];
    #pragma unroll
    for (int nt = 0; nt < 6; ++nt){
        int n = wv*96 + nt*16 + col;
        #pragma unroll
        for (int kq = 0; kq < 4; ++kq){
            const float* wr = w_hh + n*HH + kq*32 + quad*8;
            f16x8 v;
            #pragma unroll
            for (int j = 0; j < 8; ++j) v[j] = (_Float16)wr[j];
            bfr[nt][kq] = v;
        }
    }

    int cc = tid & 127, sgrp = tid >> 7;
    float bhr = b_hh[cc], bhz = b_hh[128 + cc], bhn = b_hh[256 + cc];

    float xc[2][3], xn_[2][3];
    {
        const _Float16* base = XP + (size_t)(row0)*G3 + cc;
        #pragma unroll
        for (int sp = 0; sp < 2; ++sp){
            int seq = sgrp + 2*sp;
            xc[sp][0] = (float)base[seq*G3];
            xc[sp][1] = (float)base[seq*G3 + 128];
            xc[sp][2] = (float)base[seq*G3 + 256];
        }
    }
    __syncthreads();

    for (int d = 0; d < DD; ++d){
        if (d < DD-1){
            const _Float16* base = XP + ((size_t)(d+1)*NN + row0)*G3 + cc;
            #pragma unroll
            for (int sp = 0; sp < 2; ++sp){
                int seq = sgrp + 2*sp;
                xn_[sp][0] = (float)base[seq*G3];
                xn_[sp][1] = (float)base[seq*G3 + 128];
                xn_[sp][2] = (float)base[seq*G3 + 256];
            }
        }
        f16x8 a[4];
        #pragma unroll
        for (int kq = 0; kq < 4; ++kq)
            a[kq] = *(const f16x8*)&h_hf[col][kq*32 + quad*8];
        f32x4 acc[6];
        #pragma unroll
        for (int nt = 0; nt < 6; ++nt){
            f32x4 c = {0.0f, 0.0f, 0.0f, 0.0f};
            #pragma unroll
            for (int kq = 0; kq < 4; ++kq)
                c = __builtin_amdgcn_mfma_f32_16x16x32_f16(a[kq], bfr[nt][kq], c, 0, 0, 0);
            acc[nt] = c;
        }
        if (quad == 0){
            #pragma unroll
            for (int nt = 0; nt < 6; ++nt){
                int n0 = wv*96 + nt*16 + col;
                #pragma unroll
                for (int reg = 0; reg < 4; ++reg)
                    hp_lds[reg][n0] = acc[nt][reg];
            }
        }
        __syncthreads();
        #pragma unroll
        for (int sp = 0; sp < 2; ++sp){
            int seq = sgrp + 2*sp;
            float hr = hp_lds[seq][cc]       + bhr;
            float hz = hp_lds[seq][cc + 128] + bhz;
            float hn = hp_lds[seq][cc + 256] + bhn;
            float r  = sigmoidf_(xc[sp][0] + hr);
            float z  = sigmoidf_(xc[sp][1] + hz);
            float n  = tanhf_(xc[sp][2] + r*hn);
            float ho = h_f32[seq][cc];
            float hnew = (1.0f - z)*n + z*ho;
            h_f32[seq][cc] = hnew;
            h_hf[seq][cc]  = (_Float16)hnew;
        }
        #pragma unroll
        for (int sp = 0; sp < 2; ++sp){
            xc[sp][0] = xn_[sp][0]; xc[sp][1] = xn_[sp][1]; xc[sp][2] = xn_[sp][2];
        }
        __syncthreads();
    }

    if (tid < 64){
        int c2 = tid;
        #pragma unroll 1
        for (int r = 0; r < 4; ++r){
            float a0 = 0.0f, a1 = 0.0f;
            #pragma unroll 8
            for (int k = 0; k < 64; ++k){
                a0 = fmaf(h_f32[r][k],      w1[k*64 + c2],        a0);
                a1 = fmaf(h_f32[r][64 + k], w1[(64 + k)*64 + c2], a1);
            }
            float hid = fmaxf(a0 + a1 + b1[c2], 0.0f);
            float o = hid * w2[c2];
            #pragma unroll
            for (int off = 1; off < 64; off <<= 1) o += __shfl_xor(o, off, 64);
            if (c2 == 0) out[row0 + r] = o + b2[0];
        }
    }
}

extern "C" void kernel_launch(void* const* d_in, const int* in_sizes, int n_in,
                              void* d_out, int out_size, void* d_ws, size_t ws_size,
                              hipStream_t stream) {
    const float* x    = (const float*)d_in[0];
    const int*   mask = (const int*)d_in[1];
    const float* wq   = (const float*)d_in[2];
    const float* bq   = (const float*)d_in[3];
    const float* wk   = (const float*)d_in[4];
    const float* bk   = (const float*)d_in[5];
    const float* wv   = (const float*)d_in[6];
    const float* bv   = (const float*)d_in[7];
    const float* ln_g = (const float*)d_in[8];
    const float* ln_b = (const float*)d_in[9];
    const float* w_ih = (const float*)d_in[10];
    const float* w_hh = (const float*)d_in[11];
    const float* b_ih = (const float*)d_in[12];
    const float* b_hh = (const float*)d_in[13];
    const float* w1   = (const float*)d_in[14];
    const float* b1   = (const float*)d_in[15];
    const float* w2   = (const float*)d_in[16];
    const float* b2   = (const float*)d_in[17];

    float* ws = (float*)d_ws;
    // phase 1 layout (floats):
    _Float16* Qh  = (_Float16*)ws;                    // 7,864,320 f16 = [0, 3,932,160)
    _Float16* Kh  = (_Float16*)(ws + 3932160);        // 7,864,320 f16 = [3,932,160, 7,864,320)
    float*    V   = ws + 7864320;                     // 7,864,320 f32
    float*    Wg  = ws + 15728640;                    //   122,880 f32
    // phase 2: XP aliases the whole dead Q/K/V/Wg region
    _Float16* XP  = (_Float16*)ws;                    // 47,185,920 f16 = [0, 23,592,960)
    float* market = ws + 23592960;                    //    15,360 f32
    _Float16* wf16= (_Float16*)(ws + 23608320);       //    86,016 f16
    _Float16* wqkv= (_Float16*)(ws + 23651328);       //    30,720 f16
    // total ~94.7 MB

    hipMemsetAsync(Wg, 0, 122880*sizeof(float), stream);
    prep_kernel<<<456, 256, 0, stream>>>(w_ih, wq, wk, wv, wf16, wqkv);
    qkv_kernel<<<1920, 256, 0, stream>>>(x, wqkv, bq, bk, bv, Qh, Kh, V);
    attn_kernel<<<1920, 256, 0, stream>>>(Qh, Kh, mask, Wg);
    market_kernel<<<240, 64, 0, stream>>>(Wg, V, mask, market);
    xproj_kernel<<<1920, 512, 0, stream>>>(x, market, ln_g, ln_b, wf16, b_ih, XP);
    gru_kernel<<<512, 256, 0, stream>>>(XP, w_hh, b_hh, w1, b1, w2, b2, (float*)d_out);
}

// Round 6
// 399.713 us; speedup vs baseline: 34.9978x; 1.2085x over previous
//
#include <hip/hip_runtime.h>
#include <hip/hip_bf16.h>
#include <math.h>

#define BB 4
#define DD 60
#define SS 512
#define FF 158
#define CC 64
#define HH 128
#define FC 222      // F + C
#define G3 384      // 3H
#define NN 2048     // B*S
#define BDN 240     // B*D

typedef _Float16 f16x8 __attribute__((ext_vector_type(8)));
typedef float f32x4 __attribute__((ext_vector_type(4)));

__device__ __forceinline__ float sigmoidf_(float x){ return 1.0f/(1.0f+__expf(-x)); }
__device__ __forceinline__ float tanhf_(float x){
    float e = __expf(-2.0f*fabsf(x));
    float t = (1.0f - e)/(1.0f + e);
    return copysignf(t, x);
}

// ---------------- prep: wf16 (384x224) for xproj, wqkv (192x160) for qkv --------------
__global__ void prep_kernel(const float* __restrict__ w_ih,
                            const float* __restrict__ wq, const float* __restrict__ wk,
                            const float* __restrict__ wv,
                            _Float16* __restrict__ wf16, _Float16* __restrict__ wqkv){
    int idx = blockIdx.x*256 + threadIdx.x;
    if (idx < 384*224){
        int n = idx / 224, k = idx % 224;
        wf16[idx] = (k < FC) ? (_Float16)w_ih[n*FC + k] : (_Float16)0.0f;
    } else {
        int i2 = idx - 384*224;
        if (i2 < 192*160){
            int n = i2 / 160, k = i2 % 160;
            float v = 0.0f;
            if (k < FF){
                if (n < 64)       v = wq[k*CC + n];
                else if (n < 128) v = wk[k*CC + (n-64)];
                else              v = wv[k*CC + (n-128)];
            }
            wqkv[i2] = (_Float16)v;
        }
    }
}

// ---------------- QKV via f16 MFMA: 64 rows/block, 256 thr (4 waves) ------------------
__global__ __launch_bounds__(256) void qkv_kernel(const float* __restrict__ x,
                           const _Float16* __restrict__ wqkv,
                           const float* __restrict__ bq, const float* __restrict__ bk,
                           const float* __restrict__ bv,
                           _Float16* __restrict__ Qh, _Float16* __restrict__ Kh,
                           float* __restrict__ V){
    __shared__ _Float16 xa[5][64][40];   // fragment layout, 25.6 KB
    int tid  = threadIdx.x;
    int lane = tid & 63, wv = tid >> 6;
    int col  = lane & 15, quad = lane >> 4;
    int row0 = blockIdx.x * 64;

    f16x8 bfr[3][5];
    #pragma unroll
    for (int nt = 0; nt < 3; ++nt){
        int n = wv*48 + nt*16 + col;
        #pragma unroll
        for (int kq = 0; kq < 5; ++kq)
            bfr[nt][kq] = *(const f16x8*)&wqkv[n*160 + kq*32 + quad*8];
    }

    for (int i = tid; i < 64*160; i += 256){
        int r = i / 160, k = i % 160;
        float v = (k < FF) ? x[(size_t)(row0 + r)*FF + k] : 0.0f;
        xa[k >> 5][r][k & 31] = (_Float16)v;
    }
    __syncthreads();

    float bias[3];
    #pragma unroll
    for (int nt = 0; nt < 3; ++nt){
        int n = wv*48 + nt*16 + col;
        bias[nt] = (n < 64) ? bq[n] : (n < 128 ? bk[n-64] : bv[n-128]);
    }

    #pragma unroll 1
    for (int mt = 0; mt < 4; ++mt){
        f16x8 a[5];
        #pragma unroll
        for (int kq = 0; kq < 5; ++kq)
            a[kq] = *(const f16x8*)&xa[kq][mt*16 + col][quad*8];
        #pragma unroll
        for (int nt = 0; nt < 3; ++nt){
            f32x4 c = {0.0f, 0.0f, 0.0f, 0.0f};
            #pragma unroll
            for (int kq = 0; kq < 5; ++kq)
                c = __builtin_amdgcn_mfma_f32_16x16x32_f16(a[kq], bfr[nt][kq], c, 0, 0, 0);
            int n = wv*48 + nt*16 + col;
            #pragma unroll
            for (int reg = 0; reg < 4; ++reg){
                int row = row0 + mt*16 + quad*4 + reg;
                float val = c[reg] + bias[nt];
                if (n < 64)       Qh[(size_t)row*CC + n]       = (_Float16)val;
                else if (n < 128) Kh[(size_t)row*CC + (n-64)]  = (_Float16)val;
                else              V [(size_t)row*CC + (n-128)] = val;
            }
        }
    }
}

// ---------------- attention: one block per bd, K staged in LDS once -------------------
// 240 blocks x 512 thr (8 waves). Wave wv owns 64 query rows [wv*64, wv*64+64).
// K in LDS fragment layout kf[kq][t][32] (conflict-optimal). Two passes; B-frags
// loaded once per key-tile and reused across 4 A-frag sets. W accum via LDS atomics.
__global__ __launch_bounds__(512) void attn_kernel(const _Float16* __restrict__ Qh,
                                                   const _Float16* __restrict__ Kh,
                                                   const int* __restrict__ mask,
                                                   float* __restrict__ Wg){
    __shared__ _Float16 kf[2][512][32];   // 64 KB
    __shared__ float w_sh[512];
    __shared__ float mk_lds[512];

    int tid  = threadIdx.x;
    int bd   = blockIdx.x;
    int lane = tid & 63, wv = tid >> 6;
    int col  = lane & 15, quad = lane >> 4;

    const _Float16* qb = Qh + (size_t)(bd*SS)*CC;
    const _Float16* kb = Kh + (size_t)(bd*SS)*CC;

    {
        int t = tid;
        w_sh[t] = 0.0f;
        mk_lds[t] = (mask[bd*SS + t] != 0) ? 1.0f : 0.0f;
    }
    // stage K: 4096 chunks of 8 f16 (16 B); i -> t=i>>3, ch=i&7
    for (int i = tid; i < 4096; i += 512){
        int t = i >> 3, ch = i & 7;
        *(f16x8*)&kf[ch >> 2][t][(ch & 3)*8] = *(const f16x8*)&kb[t*CC + ch*8];
    }

    // A fragments: 4 sets of 16 rows
    f16x8 a0[4], a1[4];
    #pragma unroll
    for (int af = 0; af < 4; ++af){
        int row = wv*64 + af*16 + col;
        a0[af] = *(const f16x8*)&qb[row*CC + quad*8];
        a1[af] = *(const f16x8*)&qb[row*CC + 32 + quad*8];
    }
    __syncthreads();

    // ---- pass 0: row sums l ----
    float lacc[4][4] = {{0,0,0,0},{0,0,0,0},{0,0,0,0},{0,0,0,0}};
    #pragma unroll 2
    for (int kt = 0; kt < 32; ++kt){
        f16x8 b0 = *(const f16x8*)&kf[0][kt*16 + col][quad*8];
        f16x8 b1 = *(const f16x8*)&kf[1][kt*16 + col][quad*8];
        float mkv = mk_lds[kt*16 + col];
        #pragma unroll
        for (int af = 0; af < 4; ++af){
            f32x4 c = {0.0f, 0.0f, 0.0f, 0.0f};
            c = __builtin_amdgcn_mfma_f32_16x16x32_f16(a0[af], b0, c, 0, 0, 0);
            c = __builtin_amdgcn_mfma_f32_16x16x32_f16(a1[af], b1, c, 0, 0, 0);
            #pragma unroll
            for (int reg = 0; reg < 4; ++reg)
                lacc[af][reg] += __expf(c[reg]*0.125f) * mkv;
        }
    }
    // reduce over the 16 col-lanes (lane bits 0..3)
    float crv[4][4];
    #pragma unroll
    for (int af = 0; af < 4; ++af){
        #pragma unroll
        for (int reg = 0; reg < 4; ++reg){
            float l = lacc[af][reg];
            l += __shfl_xor(l, 1, 64);
            l += __shfl_xor(l, 2, 64);
            l += __shfl_xor(l, 4, 64);
            l += __shfl_xor(l, 8, 64);
            int row = wv*64 + af*16 + quad*4 + reg;
            crv[af][reg] = mk_lds[row] / l;
        }
    }

    // ---- pass 1: accumulate W columns ----
    #pragma unroll 2
    for (int kt = 0; kt < 32; ++kt){
        f16x8 b0 = *(const f16x8*)&kf[0][kt*16 + col][quad*8];
        f16x8 b1 = *(const f16x8*)&kf[1][kt*16 + col][quad*8];
        float s = 0.0f;
        #pragma unroll
        for (int af = 0; af < 4; ++af){
            f32x4 c = {0.0f, 0.0f, 0.0f, 0.0f};
            c = __builtin_amdgcn_mfma_f32_16x16x32_f16(a0[af], b0, c, 0, 0, 0);
            c = __builtin_amdgcn_mfma_f32_16x16x32_f16(a1[af], b1, c, 0, 0, 0);
            #pragma unroll
            for (int reg = 0; reg < 4; ++reg)
                s = fmaf(__expf(c[reg]*0.125f), crv[af][reg], s);
        }
        s += __shfl_xor(s, 16, 64);
        s += __shfl_xor(s, 32, 64);
        if (quad == 0)
            atomicAdd(&w_sh[kt*16 + col], s);
    }
    __syncthreads();
    Wg[bd*SS + tid] = w_sh[tid];
}

// ---------------- market[bd][c] = (W * key_mask) @ V / denom --------------------------
__global__ void market_kernel(const float* __restrict__ Wg, const float* __restrict__ V,
                              const int* __restrict__ mask, float* __restrict__ market){
    int bd = blockIdx.x;
    int c  = threadIdx.x; // 64 threads
    int cnt = 0;
    #pragma unroll
    for (int j = 0; j < 8; ++j) cnt += (mask[bd*SS + c + j*64] != 0) ? 1 : 0;
    #pragma unroll
    for (int o = 1; o < 64; o <<= 1) cnt += __shfl_xor(cnt, o, 64);
    float acc = 0.0f;
    for (int t = 0; t < SS; ++t){
        float mkt = (mask[bd*SS + t] != 0) ? 1.0f : 0.0f;
        acc = fmaf(Wg[bd*SS + t]*mkt, V[(size_t)(bd*SS + t)*CC + c], acc);
    }
    int dn = cnt < 1 ? 1 : cnt;
    market[bd*CC + c] = acc / (float)dn;
}

// ---------------- fused LN + x_proj f16 MFMA GEMM -------------------------------------
__global__ __launch_bounds__(512, 2) void xproj_kernel(const float* __restrict__ x,
                             const float* __restrict__ market,
                             const float* __restrict__ ln_g, const float* __restrict__ ln_b,
                             const _Float16* __restrict__ wf16, const float* __restrict__ b_ih,
                             _Float16* __restrict__ XP){
    __shared__ _Float16 aug[7][64][32];   // 28 KB
    int tid  = threadIdx.x;
    int lane = tid & 63, wv = tid >> 6;
    int col  = lane & 15, quad = lane >> 4;
    int row0 = blockIdx.x * 64;

    f16x8 bfr[3][7];
    #pragma unroll
    for (int nt = 0; nt < 3; ++nt){
        int n = wv*48 + nt*16 + col;
        #pragma unroll
        for (int kq = 0; kq < 7; ++kq)
            bfr[nt][kq] = *(const f16x8*)&wf16[n*224 + kq*32 + quad*8];
    }

    {
        int wrow = wv*8 + (lane >> 3);
        int g    = lane & 7;
        int row  = row0 + wrow;
        int d = row / NN, n = row % NN;
        int b = n >> 9, s = n & 511;
        const float* xr = &x[((size_t)((b*DD + d)*SS) + s)*FF];
        const float* mr = &market[(b*DD + d)*CC];
        float v[28];
        float sum = 0.0f, sq = 0.0f;
        #pragma unroll
        for (int j = 0; j < 28; ++j){
            int f = g + 8*j;
            float vv = 0.0f;
            if (f < FF) vv = xr[f];
            else if (f < FC) vv = mr[f - FF];
            v[j] = vv;
            sum += vv; sq += vv*vv;
        }
        sum += __shfl_xor(sum,1,64); sq += __shfl_xor(sq,1,64);
        sum += __shfl_xor(sum,2,64); sq += __shfl_xor(sq,2,64);
        sum += __shfl_xor(sum,4,64); sq += __shfl_xor(sq,4,64);
        float mu   = sum * (1.0f/222.0f);
        float var  = sq * (1.0f/222.0f) - mu*mu;
        float rstd = rsqrtf(var + 1e-5f);
        #pragma unroll
        for (int j = 0; j < 28; ++j){
            int f = g + 8*j;
            float val = (f < FC) ? ((v[j]-mu)*rstd*ln_g[f] + ln_b[f]) : 0.0f;
            aug[f>>5][wrow][f&31] = (_Float16)val;
        }
    }
    __syncthreads();

    float bias[3];
    #pragma unroll
    for (int nt = 0; nt < 3; ++nt) bias[nt] = b_ih[wv*48 + nt*16 + col];
    #pragma unroll 1
    for (int mt = 0; mt < 4; ++mt){
        f16x8 a[7];
        #pragma unroll
        for (int kq = 0; kq < 7; ++kq)
            a[kq] = *(const f16x8*)&aug[kq][mt*16 + col][quad*8];
        #pragma unroll
        for (int nt = 0; nt < 3; ++nt){
            f32x4 c = {0.0f, 0.0f, 0.0f, 0.0f};
            #pragma unroll
            for (int kq = 0; kq < 7; ++kq)
                c = __builtin_amdgcn_mfma_f32_16x16x32_f16(a[kq], bfr[nt][kq], c, 0, 0, 0);
            int nn = wv*48 + nt*16 + col;
            #pragma unroll
            for (int reg = 0; reg < 4; ++reg){
                int m = quad*4 + reg;
                XP[(size_t)(row0 + mt*16 + m)*G3 + nn] = (_Float16)(c[reg] + bias[nt]);
            }
        }
    }
}

// ---------------- persistent GRU: f16 MFMA recurrent GEMM + fused head ----------------
__global__ __launch_bounds__(256, 2) void gru_kernel(const _Float16* __restrict__ XP,
                                                     const float* __restrict__ w_hh,
                                                     const float* __restrict__ b_hh,
                                                     const float* __restrict__ w1, const float* __restrict__ b1,
                                                     const float* __restrict__ w2, const float* __restrict__ b2,
                                                     float* __restrict__ out){
    __shared__ _Float16 h_hf[16][136];
    __shared__ float hp_lds[4][392];
    __shared__ float h_f32[4][132];

    int tid  = threadIdx.x;
    int lane = tid & 63, wv = tid >> 6;
    int col  = lane & 15, quad = lane >> 4;
    int row0 = blockIdx.x * 4;

    for (int i = tid; i < 16*136; i += 256) ((_Float16*)h_hf)[i] = (_Float16)0.0f;
    for (int i = tid; i < 4*132; i += 256) ((float*)h_f32)[i] = 0.0f;

    f16x8 bfr[6][4];
    #pragma unroll
    for (int nt = 0; nt < 6; ++nt){
        int n = wv*96 + nt*16 + col;
        #pragma unroll
        for (int kq = 0; kq < 4; ++kq){
            const float* wr = w_hh + n*HH + kq*32 + quad*8;
            f16x8 v;
            #pragma unroll
            for (int j = 0; j < 8; ++j) v[j] = (_Float16)wr[j];
            bfr[nt][kq] = v;
        }
    }

    int cc = tid & 127, sgrp = tid >> 7;
    float bhr = b_hh[cc], bhz = b_hh[128 + cc], bhn = b_hh[256 + cc];

    float xc[2][3], xn_[2][3];
    {
        const _Float16* base = XP + (size_t)(row0)*G3 + cc;
        #pragma unroll
        for (int sp = 0; sp < 2; ++sp){
            int seq = sgrp + 2*sp;
            xc[sp][0] = (float)base[seq*G3];
            xc[sp][1] = (float)base[seq*G3 + 128];
            xc[sp][2] = (float)base[seq*G3 + 256];
        }
    }
    __syncthreads();

    for (int d = 0; d < DD; ++d){
        if (d < DD-1){
            const _Float16* base = XP + ((size_t)(d+1)*NN + row0)*G3 + cc;
            #pragma unroll
            for (int sp = 0; sp < 2; ++sp){
                int seq = sgrp + 2*sp;
                xn_[sp][0] = (float)base[seq*G3];
                xn_[sp][1] = (float)base[seq*G3 + 128];
                xn_[sp][2] = (float)base[seq*G3 + 256];
            }
        }
        f16x8 a[4];
        #pragma unroll
        for (int kq = 0; kq < 4; ++kq)
            a[kq] = *(const f16x8*)&h_hf[col][kq*32 + quad*8];
        f32x4 acc[6];
        #pragma unroll
        for (int nt = 0; nt < 6; ++nt){
            f32x4 c = {0.0f, 0.0f, 0.0f, 0.0f};
            #pragma unroll
            for (int kq = 0; kq < 4; ++kq)
                c = __builtin_amdgcn_mfma_f32_16x16x32_f16(a[kq], bfr[nt][kq], c, 0, 0, 0);
            acc[nt] = c;
        }
        if (quad == 0){
            #pragma unroll
            for (int nt = 0; nt < 6; ++nt){
                int n0 = wv*96 + nt*16 + col;
                #pragma unroll
                for (int reg = 0; reg < 4; ++reg)
                    hp_lds[reg][n0] = acc[nt][reg];
            }
        }
        __syncthreads();
        #pragma unroll
        for (int sp = 0; sp < 2; ++sp){
            int seq = sgrp + 2*sp;
            float hr = hp_lds[seq][cc]       + bhr;
            float hz = hp_lds[seq][cc + 128] + bhz;
            float hn = hp_lds[seq][cc + 256] + bhn;
            float r  = sigmoidf_(xc[sp][0] + hr);
            float z  = sigmoidf_(xc[sp][1] + hz);
            float n  = tanhf_(xc[sp][2] + r*hn);
            float ho = h_f32[seq][cc];
            float hnew = (1.0f - z)*n + z*ho;
            h_f32[seq][cc] = hnew;
            h_hf[seq][cc]  = (_Float16)hnew;
        }
        #pragma unroll
        for (int sp = 0; sp < 2; ++sp){
            xc[sp][0] = xn_[sp][0]; xc[sp][1] = xn_[sp][1]; xc[sp][2] = xn_[sp][2];
        }
        __syncthreads();
    }

    if (tid < 64){
        int c2 = tid;
        #pragma unroll 1
        for (int r = 0; r < 4; ++r){
            float a0 = 0.0f, a1 = 0.0f;
            #pragma unroll 8
            for (int k = 0; k < 64; ++k){
                a0 = fmaf(h_f32[r][k],      w1[k*64 + c2],        a0);
                a1 = fmaf(h_f32[r][64 + k], w1[(64 + k)*64 + c2], a1);
            }
            float hid = fmaxf(a0 + a1 + b1[c2], 0.0f);
            float o = hid * w2[c2];
            #pragma unroll
            for (int off = 1; off < 64; off <<= 1) o += __shfl_xor(o, off, 64);
            if (c2 == 0) out[row0 + r] = o + b2[0];
        }
    }
}

extern "C" void kernel_launch(void* const* d_in, const int* in_sizes, int n_in,
                              void* d_out, int out_size, void* d_ws, size_t ws_size,
                              hipStream_t stream) {
    const float* x    = (const float*)d_in[0];
    const int*   mask = (const int*)d_in[1];
    const float* wq   = (const float*)d_in[2];
    const float* bq   = (const float*)d_in[3];
    const float* wk   = (const float*)d_in[4];
    const float* bk   = (const float*)d_in[5];
    const float* wv   = (const float*)d_in[6];
    const float* bv   = (const float*)d_in[7];
    const float* ln_g = (const float*)d_in[8];
    const float* ln_b = (const float*)d_in[9];
    const float* w_ih = (const float*)d_in[10];
    const float* w_hh = (const float*)d_in[11];
    const float* b_ih = (const float*)d_in[12];
    const float* b_hh = (const float*)d_in[13];
    const float* w1   = (const float*)d_in[14];
    const float* b1   = (const float*)d_in[15];
    const float* w2   = (const float*)d_in[16];
    const float* b2   = (const float*)d_in[17];

    float* ws = (float*)d_ws;
    // phase 1 layout (floats):
    _Float16* Qh  = (_Float16*)ws;                    // 7,864,320 f16 = [0, 3,932,160)
    _Float16* Kh  = (_Float16*)(ws + 3932160);        // 7,864,320 f16 = [3,932,160, 7,864,320)
    float*    V   = ws + 7864320;                     // 7,864,320 f32
    float*    Wg  = ws + 15728640;                    //   122,880 f32
    // phase 2: XP aliases the whole dead Q/K/V/Wg region
    _Float16* XP  = (_Float16*)ws;                    // 47,185,920 f16 = [0, 23,592,960)
    float* market = ws + 23592960;                    //    15,360 f32
    _Float16* wf16= (_Float16*)(ws + 23608320);       //    86,016 f16
    _Float16* wqkv= (_Float16*)(ws + 23651328);       //    30,720 f16
    // total ~94.7 MB

    prep_kernel<<<456, 256, 0, stream>>>(w_ih, wq, wk, wv, wf16, wqkv);
    qkv_kernel<<<1920, 256, 0, stream>>>(x, wqkv, bq, bk, bv, Qh, Kh, V);
    attn_kernel<<<240, 512, 0, stream>>>(Qh, Kh, mask, Wg);
    market_kernel<<<240, 64, 0, stream>>>(Wg, V, mask, market);
    xproj_kernel<<<1920, 512, 0, stream>>>(x, market, ln_g, ln_b, wf16, b_ih, XP);
    gru_kernel<<<512, 256, 0, stream>>>(XP, w_hh, b_hh, w1, b1, w2, b2, (float*)d_out);
}

// Round 7
// 367.718 us; speedup vs baseline: 38.0429x; 1.0870x over previous
//
#include <hip/hip_runtime.h>
#include <hip/hip_bf16.h>
#include <math.h>

#define BB 4
#define DD 60
#define SS 512
#define FF 158
#define CC 64
#define HH 128
#define FC 222      // F + C
#define G3 384      // 3H
#define NN 2048     // B*S
#define BDN 240     // B*D

typedef _Float16 f16x8 __attribute__((ext_vector_type(8)));
typedef float f32x4 __attribute__((ext_vector_type(4)));

__device__ __forceinline__ float sigmoidf_(float x){ return 1.0f/(1.0f+__expf(-x)); }
__device__ __forceinline__ float tanhf_(float x){
    float e = __expf(-2.0f*fabsf(x));
    float t = (1.0f - e)/(1.0f + e);
    return copysignf(t, x);
}

// ---- prep: wf16 (384x224) xproj, wqkv (192x160) qkv, whh16 (384x128) gru -------------
__global__ void prep_kernel(const float* __restrict__ w_ih,
                            const float* __restrict__ wq, const float* __restrict__ wk,
                            const float* __restrict__ wv, const float* __restrict__ w_hh,
                            _Float16* __restrict__ wf16, _Float16* __restrict__ wqkv,
                            _Float16* __restrict__ whh16){
    int idx = blockIdx.x*256 + threadIdx.x;
    if (idx < 384*224){
        int n = idx / 224, k = idx % 224;
        wf16[idx] = (k < FC) ? (_Float16)w_ih[n*FC + k] : (_Float16)0.0f;
    } else if (idx < 384*224 + 192*160){
        int i2 = idx - 384*224;
        int n = i2 / 160, k = i2 % 160;
        float v = 0.0f;
        if (k < FF){
            if (n < 64)       v = wq[k*CC + n];
            else if (n < 128) v = wk[k*CC + (n-64)];
            else              v = wv[k*CC + (n-128)];
        }
        wqkv[i2] = (_Float16)v;
    } else {
        int i3 = idx - (384*224 + 192*160);
        if (i3 < 384*128)
            whh16[i3] = (_Float16)w_hh[i3];
    }
}

// ---------------- QKV via f16 MFMA: 64 rows/block, 256 thr (4 waves) ------------------
__global__ __launch_bounds__(256) void qkv_kernel(const float* __restrict__ x,
                           const _Float16* __restrict__ wqkv,
                           const float* __restrict__ bq, const float* __restrict__ bk,
                           const float* __restrict__ bv,
                           _Float16* __restrict__ Qh, _Float16* __restrict__ Kh,
                           float* __restrict__ V){
    __shared__ _Float16 xa[5][64][40];   // fragment layout, 25.6 KB
    int tid  = threadIdx.x;
    int lane = tid & 63, wv = tid >> 6;
    int col  = lane & 15, quad = lane >> 4;
    int row0 = blockIdx.x * 64;

    f16x8 bfr[3][5];
    #pragma unroll
    for (int nt = 0; nt < 3; ++nt){
        int n = wv*48 + nt*16 + col;
        #pragma unroll
        for (int kq = 0; kq < 5; ++kq)
            bfr[nt][kq] = *(const f16x8*)&wqkv[n*160 + kq*32 + quad*8];
    }

    for (int i = tid; i < 64*160; i += 256){
        int r = i / 160, k = i % 160;
        float v = (k < FF) ? x[(size_t)(row0 + r)*FF + k] : 0.0f;
        xa[k >> 5][r][k & 31] = (_Float16)v;
    }
    __syncthreads();

    float bias[3];
    #pragma unroll
    for (int nt = 0; nt < 3; ++nt){
        int n = wv*48 + nt*16 + col;
        bias[nt] = (n < 64) ? bq[n] : (n < 128 ? bk[n-64] : bv[n-128]);
    }

    #pragma unroll 1
    for (int mt = 0; mt < 4; ++mt){
        f16x8 a[5];
        #pragma unroll
        for (int kq = 0; kq < 5; ++kq)
            a[kq] = *(const f16x8*)&xa[kq][mt*16 + col][quad*8];
        #pragma unroll
        for (int nt = 0; nt < 3; ++nt){
            f32x4 c = {0.0f, 0.0f, 0.0f, 0.0f};
            #pragma unroll
            for (int kq = 0; kq < 5; ++kq)
                c = __builtin_amdgcn_mfma_f32_16x16x32_f16(a[kq], bfr[nt][kq], c, 0, 0, 0);
            int n = wv*48 + nt*16 + col;
            #pragma unroll
            for (int reg = 0; reg < 4; ++reg){
                int row = row0 + mt*16 + quad*4 + reg;
                float val = c[reg] + bias[nt];
                if (n < 64)       Qh[(size_t)row*CC + n]       = (_Float16)val;
                else if (n < 128) Kh[(size_t)row*CC + (n-64)]  = (_Float16)val;
                else              V [(size_t)row*CC + (n-128)] = val;
            }
        }
    }
}

// ---------------- attention + fused market: one block per bd --------------------------
// 240 blocks x 512 thr (8 waves). K staged once in LDS fragment layout. Two passes,
// then market[bd] = (W*mask)@V/denom computed in-block (W, mask already in LDS).
__global__ __launch_bounds__(512) void attn_kernel(const _Float16* __restrict__ Qh,
                                                   const _Float16* __restrict__ Kh,
                                                   const int* __restrict__ mask,
                                                   const float* __restrict__ V,
                                                   float* __restrict__ market){
    __shared__ _Float16 kf[2][512][32];   // 64 KB
    __shared__ float w_sh[512];
    __shared__ float mk_lds[512];

    int tid  = threadIdx.x;
    int bd   = blockIdx.x;
    int lane = tid & 63, wv = tid >> 6;
    int col  = lane & 15, quad = lane >> 4;

    const _Float16* qb = Qh + (size_t)(bd*SS)*CC;
    const _Float16* kb = Kh + (size_t)(bd*SS)*CC;

    {
        int t = tid;
        w_sh[t] = 0.0f;
        mk_lds[t] = (mask[bd*SS + t] != 0) ? 1.0f : 0.0f;
    }
    for (int i = tid; i < 4096; i += 512){
        int t = i >> 3, ch = i & 7;
        *(f16x8*)&kf[ch >> 2][t][(ch & 3)*8] = *(const f16x8*)&kb[t*CC + ch*8];
    }

    f16x8 a0[4], a1[4];
    #pragma unroll
    for (int af = 0; af < 4; ++af){
        int row = wv*64 + af*16 + col;
        a0[af] = *(const f16x8*)&qb[row*CC + quad*8];
        a1[af] = *(const f16x8*)&qb[row*CC + 32 + quad*8];
    }
    __syncthreads();

    // ---- pass 0: row sums l ----
    float lacc[4][4] = {{0,0,0,0},{0,0,0,0},{0,0,0,0},{0,0,0,0}};
    #pragma unroll 2
    for (int kt = 0; kt < 32; ++kt){
        f16x8 b0 = *(const f16x8*)&kf[0][kt*16 + col][quad*8];
        f16x8 b1 = *(const f16x8*)&kf[1][kt*16 + col][quad*8];
        float mkv = mk_lds[kt*16 + col];
        #pragma unroll
        for (int af = 0; af < 4; ++af){
            f32x4 c = {0.0f, 0.0f, 0.0f, 0.0f};
            c = __builtin_amdgcn_mfma_f32_16x16x32_f16(a0[af], b0, c, 0, 0, 0);
            c = __builtin_amdgcn_mfma_f32_16x16x32_f16(a1[af], b1, c, 0, 0, 0);
            #pragma unroll
            for (int reg = 0; reg < 4; ++reg)
                lacc[af][reg] += __expf(c[reg]*0.125f) * mkv;
        }
    }
    float crv[4][4];
    #pragma unroll
    for (int af = 0; af < 4; ++af){
        #pragma unroll
        for (int reg = 0; reg < 4; ++reg){
            float l = lacc[af][reg];
            l += __shfl_xor(l, 1, 64);
            l += __shfl_xor(l, 2, 64);
            l += __shfl_xor(l, 4, 64);
            l += __shfl_xor(l, 8, 64);
            int row = wv*64 + af*16 + quad*4 + reg;
            crv[af][reg] = mk_lds[row] / l;
        }
    }

    // ---- pass 1: accumulate W columns ----
    #pragma unroll 2
    for (int kt = 0; kt < 32; ++kt){
        f16x8 b0 = *(const f16x8*)&kf[0][kt*16 + col][quad*8];
        f16x8 b1 = *(const f16x8*)&kf[1][kt*16 + col][quad*8];
        float s = 0.0f;
        #pragma unroll
        for (int af = 0; af < 4; ++af){
            f32x4 c = {0.0f, 0.0f, 0.0f, 0.0f};
            c = __builtin_amdgcn_mfma_f32_16x16x32_f16(a0[af], b0, c, 0, 0, 0);
            c = __builtin_amdgcn_mfma_f32_16x16x32_f16(a1[af], b1, c, 0, 0, 0);
            #pragma unroll
            for (int reg = 0; reg < 4; ++reg)
                s = fmaf(__expf(c[reg]*0.125f), crv[af][reg], s);
        }
        s += __shfl_xor(s, 16, 64);
        s += __shfl_xor(s, 32, 64);
        if (quad == 0)
            atomicAdd(&w_sh[kt*16 + col], s);
    }
    __syncthreads();   // w_sh final; all kf reads complete -> safe to reuse kf as scratch

    // ---- fused market ----
    float* msum = (float*)kf;   // 2 KB scratch in dead K region
    {
        int c = tid & 63, grp = tid >> 6;
        const float* vb = V + (size_t)(bd*SS)*CC;
        float acc = 0.0f;
        int t0 = grp*64;
        #pragma unroll 4
        for (int t = t0; t < t0 + 64; ++t)
            acc = fmaf(w_sh[t]*mk_lds[t], vb[(size_t)t*CC + c], acc);
        msum[grp*64 + c] = acc;
    }
    __syncthreads();
    if (tid < 64){
        float s = 0.0f;
        #pragma unroll
        for (int g = 0; g < 8; ++g) s += msum[g*64 + tid];
        float cnt = 0.0f;
        #pragma unroll
        for (int j = 0; j < 8; ++j) cnt += mk_lds[tid + 64*j];
        #pragma unroll
        for (int o = 1; o < 64; o <<= 1) cnt += __shfl_xor(cnt, o, 64);
        market[bd*CC + tid] = s / fmaxf(cnt, 1.0f);
    }
}

// ---------------- fused LN + x_proj f16 MFMA GEMM -------------------------------------
__global__ __launch_bounds__(512, 2) void xproj_kernel(const float* __restrict__ x,
                             const float* __restrict__ market,
                             const float* __restrict__ ln_g, const float* __restrict__ ln_b,
                             const _Float16* __restrict__ wf16, const float* __restrict__ b_ih,
                             _Float16* __restrict__ XP){
    __shared__ _Float16 aug[7][64][32];   // 28 KB
    int tid  = threadIdx.x;
    int lane = tid & 63, wv = tid >> 6;
    int col  = lane & 15, quad = lane >> 4;
    int row0 = blockIdx.x * 64;

    f16x8 bfr[3][7];
    #pragma unroll
    for (int nt = 0; nt < 3; ++nt){
        int n = wv*48 + nt*16 + col;
        #pragma unroll
        for (int kq = 0; kq < 7; ++kq)
            bfr[nt][kq] = *(const f16x8*)&wf16[n*224 + kq*32 + quad*8];
    }

    {
        int wrow = wv*8 + (lane >> 3);
        int g    = lane & 7;
        int row  = row0 + wrow;
        int d = row / NN, n = row % NN;
        int b = n >> 9, s = n & 511;
        const float* xr = &x[((size_t)((b*DD + d)*SS) + s)*FF];
        const float* mr = &market[(b*DD + d)*CC];
        float v[28];
        float sum = 0.0f, sq = 0.0f;
        #pragma unroll
        for (int j = 0; j < 28; ++j){
            int f = g + 8*j;
            float vv = 0.0f;
            if (f < FF) vv = xr[f];
            else if (f < FC) vv = mr[f - FF];
            v[j] = vv;
            sum += vv; sq += vv*vv;
        }
        sum += __shfl_xor(sum,1,64); sq += __shfl_xor(sq,1,64);
        sum += __shfl_xor(sum,2,64); sq += __shfl_xor(sq,2,64);
        sum += __shfl_xor(sum,4,64); sq += __shfl_xor(sq,4,64);
        float mu   = sum * (1.0f/222.0f);
        float var  = sq * (1.0f/222.0f) - mu*mu;
        float rstd = rsqrtf(var + 1e-5f);
        #pragma unroll
        for (int j = 0; j < 28; ++j){
            int f = g + 8*j;
            float val = (f < FC) ? ((v[j]-mu)*rstd*ln_g[f] + ln_b[f]) : 0.0f;
            aug[f>>5][wrow][f&31] = (_Float16)val;
        }
    }
    __syncthreads();

    float bias[3];
    #pragma unroll
    for (int nt = 0; nt < 3; ++nt) bias[nt] = b_ih[wv*48 + nt*16 + col];
    #pragma unroll 1
    for (int mt = 0; mt < 4; ++mt){
        f16x8 a[7];
        #pragma unroll
        for (int kq = 0; kq < 7; ++kq)
            a[kq] = *(const f16x8*)&aug[kq][mt*16 + col][quad*8];
        #pragma unroll
        for (int nt = 0; nt < 3; ++nt){
            f32x4 c = {0.0f, 0.0f, 0.0f, 0.0f};
            #pragma unroll
            for (int kq = 0; kq < 7; ++kq)
                c = __builtin_amdgcn_mfma_f32_16x16x32_f16(a[kq], bfr[nt][kq], c, 0, 0, 0);
            int nn = wv*48 + nt*16 + col;
            #pragma unroll
            for (int reg = 0; reg < 4; ++reg){
                int m = quad*4 + reg;
                XP[(size_t)(row0 + mt*16 + m)*G3 + nn] = (_Float16)(c[reg] + bias[nt]);
            }
        }
    }
}

// ---------------- persistent GRU: 1 barrier/step, wave-local gates --------------------
// 512 blocks x 256 thr (4 waves), 4 seqs/block. Wave wv owns gate columns
// cc in [wv*32, wv*32+32) for all 3 gates: MFMA N-tiles {g*128 + wv*32 + half*16}.
// hp handoff is same-wave LDS (lgkmcnt only). h double-buffered in MFMA-A fragment
// layout hfrag[2][kq][16][32] (conflict-free); h_old lives in registers.
__global__ __launch_bounds__(256, 2) void gru_kernel(const _Float16* __restrict__ XP,
                                                     const _Float16* __restrict__ whh16,
                                                     const float* __restrict__ b_hh,
                                                     const float* __restrict__ w1, const float* __restrict__ b1,
                                                     const float* __restrict__ w2, const float* __restrict__ b2,
                                                     float* __restrict__ out){
    __shared__ _Float16 hfrag[2][4][16][32];  // 8 KB
    __shared__ float hp_sh[4][3][4][32];      // wave, gate, seq, u : 6 KB
    __shared__ float h_f32[4][132];           // for head

    int tid  = threadIdx.x;
    int lane = tid & 63, wv = tid >> 6;
    int col  = lane & 15, quad = lane >> 4;
    int row0 = blockIdx.x * 4;

    for (int i = tid; i < 2*4*16*32; i += 256) ((_Float16*)hfrag)[i] = (_Float16)0.0f;

    // B fragments: 3 gates x 2 halves x 4 kq; n = g*128 + wv*32 + half*16 + col
    f16x8 bfr[3][2][4];
    #pragma unroll
    for (int g = 0; g < 3; ++g){
        #pragma unroll
        for (int hf = 0; hf < 2; ++hf){
            int n = g*128 + wv*32 + hf*16 + col;
            #pragma unroll
            for (int kq = 0; kq < 4; ++kq)
                bfr[g][hf][kq] = *(const f16x8*)&whh16[(size_t)n*HH + kq*32 + quad*8];
        }
    }

    int u  = lane & 31;
    int cc = wv*32 + u;
    int sb = lane >> 5;   // seq = j*2 + sb
    float bh0 = b_hh[cc], bh1 = b_hh[128 + cc], bh2 = b_hh[256 + cc];

    float hcur[2] = {0.0f, 0.0f};
    float xc[2][3], xn_[2][3];
    #pragma unroll
    for (int j = 0; j < 2; ++j){
        int seq = j*2 + sb;
        const _Float16* base = XP + (size_t)(row0 + seq)*G3 + cc;
        xc[j][0] = (float)base[0];
        xc[j][1] = (float)base[128];
        xc[j][2] = (float)base[256];
    }
    __syncthreads();

    for (int d = 0; d < DD; ++d){
        if (d < DD-1){
            #pragma unroll
            for (int j = 0; j < 2; ++j){
                int seq = j*2 + sb;
                const _Float16* base = XP + ((size_t)(d+1)*NN + row0 + seq)*G3 + cc;
                xn_[j][0] = (float)base[0];
                xn_[j][1] = (float)base[128];
                xn_[j][2] = (float)base[256];
            }
        }
        int rb = d & 1;
        f16x8 a[4];
        #pragma unroll
        for (int kq = 0; kq < 4; ++kq)
            a[kq] = *(const f16x8*)&hfrag[rb][kq][col][quad*8];
        #pragma unroll
        for (int g = 0; g < 3; ++g){
            #pragma unroll
            for (int hf = 0; hf < 2; ++hf){
                f32x4 c = {0.0f, 0.0f, 0.0f, 0.0f};
                #pragma unroll
                for (int kq = 0; kq < 4; ++kq)
                    c = __builtin_amdgcn_mfma_f32_16x16x32_f16(a[kq], bfr[g][hf][kq], c, 0, 0, 0);
                if (quad == 0){
                    #pragma unroll
                    for (int reg = 0; reg < 4; ++reg)
                        hp_sh[wv][g][reg][hf*16 + col] = c[reg];
                }
            }
        }
        // gates: same-wave LDS dependency only (no barrier)
        #pragma unroll
        for (int j = 0; j < 2; ++j){
            int seq = j*2 + sb;
            float hr = hp_sh[wv][0][seq][u] + bh0;
            float hz = hp_sh[wv][1][seq][u] + bh1;
            float hn = hp_sh[wv][2][seq][u] + bh2;
            float r  = sigmoidf_(xc[j][0] + hr);
            float z  = sigmoidf_(xc[j][1] + hz);
            float n  = tanhf_(xc[j][2] + r*hn);
            float hnew = (1.0f - z)*n + z*hcur[j];
            hcur[j] = hnew;
            hfrag[1 - rb][wv][seq][u] = (_Float16)hnew;
        }
        #pragma unroll
        for (int j = 0; j < 2; ++j){
            xc[j][0] = xn_[j][0]; xc[j][1] = xn_[j][1]; xc[j][2] = xn_[j][2];
        }
        __syncthreads();
    }

    #pragma unroll
    for (int j = 0; j < 2; ++j){
        int seq = j*2 + sb;
        h_f32[seq][cc] = hcur[j];
    }
    __syncthreads();

    if (tid < 64){
        int c2 = tid;
        #pragma unroll 1
        for (int r = 0; r < 4; ++r){
            float a0 = 0.0f, a1 = 0.0f;
            #pragma unroll 8
            for (int k = 0; k < 64; ++k){
                a0 = fmaf(h_f32[r][k],      w1[k*64 + c2],        a0);
                a1 = fmaf(h_f32[r][64 + k], w1[(64 + k)*64 + c2], a1);
            }
            float hid = fmaxf(a0 + a1 + b1[c2], 0.0f);
            float o = hid * w2[c2];
            #pragma unroll
            for (int off = 1; off < 64; off <<= 1) o += __shfl_xor(o, off, 64);
            if (c2 == 0) out[row0 + r] = o + b2[0];
        }
    }
}

extern "C" void kernel_launch(void* const* d_in, const int* in_sizes, int n_in,
                              void* d_out, int out_size, void* d_ws, size_t ws_size,
                              hipStream_t stream) {
    const float* x    = (const float*)d_in[0];
    const int*   mask = (const int*)d_in[1];
    const float* wq   = (const float*)d_in[2];
    const float* bq   = (const float*)d_in[3];
    const float* wk   = (const float*)d_in[4];
    const float* bk   = (const float*)d_in[5];
    const float* wv   = (const float*)d_in[6];
    const float* bv   = (const float*)d_in[7];
    const float* ln_g = (const float*)d_in[8];
    const float* ln_b = (const float*)d_in[9];
    const float* w_ih = (const float*)d_in[10];
    const float* w_hh = (const float*)d_in[11];
    const float* b_ih = (const float*)d_in[12];
    const float* b_hh = (const float*)d_in[13];
    const float* w1   = (const float*)d_in[14];
    const float* b1   = (const float*)d_in[15];
    const float* w2   = (const float*)d_in[16];
    const float* b2   = (const float*)d_in[17];

    float* ws = (float*)d_ws;
    // phase 1 (f32 index units):
    _Float16* Qh  = (_Float16*)ws;                    // f16 [0, 3,932,160)
    _Float16* Kh  = (_Float16*)(ws + 3932160);        // f16 [3,932,160, 7,864,320)
    float*    V   = ws + 7864320;                     // f32 [7,864,320, 15,728,640)
    // phase 2: XP aliases the dead Q/K/V region
    _Float16* XP  = (_Float16*)ws;                    // f16 [0, 23,592,960)
    float* market = ws + 23592960;                    //    15,360 f32
    _Float16* wf16 = (_Float16*)(ws + 23608320);      //    86,016 f16
    _Float16* wqkv = (_Float16*)(ws + 23651328);      //    30,720 f16
    _Float16* whh16= (_Float16*)(ws + 23666688);      //    49,152 f16
    // total ~94.8 MB

    prep_kernel<<<648, 256, 0, stream>>>(w_ih, wq, wk, wv, w_hh, wf16, wqkv, whh16);
    qkv_kernel<<<1920, 256, 0, stream>>>(x, wqkv, bq, bk, bv, Qh, Kh, V);
    attn_kernel<<<240, 512, 0, stream>>>(Qh, Kh, mask, V, market);
    xproj_kernel<<<1920, 512, 0, stream>>>(x, market, ln_g, ln_b, wf16, b_ih, XP);
    gru_kernel<<<512, 256, 0, stream>>>(XP, whh16, b_hh, w1, b1, w2, b2, (float*)d_out);
}